// Round 2
// baseline (2161.334 us; speedup 1.0000x reference)
//
#include <hip/hip_runtime.h>
#include <hip/hip_bf16.h>

// ---- problem constants ----
#define D_MODEL   512
#define D_STATE   128
#define D_CONV    4
#define HEADDIM   64
#define NLAYERS   2
#define D_INNER   1024
#define NHEADS    16
#define CONV_DIM  1280          // D_INNER + 2*D_STATE
#define D_IN_PROJ 2320          // 2*D_INNER + 2*D_STATE + NHEADS
#define SEQ       64
#define BATCH     512
#define NTOK      (BATCH*SEQ)   // 32768
#define FC_HID    128
#define EPS       1e-5f

using bf16 = __hip_bfloat16;
typedef __bf16 bf16x8 __attribute__((ext_vector_type(8)));
typedef float  f32x4  __attribute__((ext_vector_type(4)));

__device__ __forceinline__ float b2f(bf16 v)  { return __bfloat162float(v); }
__device__ __forceinline__ bf16  f2b(float v) { return __float2bfloat16(v); }
__device__ __forceinline__ float bflo(unsigned u){ return __builtin_bit_cast(float, u << 16); }
__device__ __forceinline__ float bfhi(unsigned u){ return __builtin_bit_cast(float, u & 0xffff0000u); }

// ---------------- embedding: h[b,s,:] = emb[x[b,s],:] + pos[s,:] (f32) ----------------
__global__ __launch_bounds__(256) void k_embed(const int* __restrict__ x,
        const float* __restrict__ emb, const float* __restrict__ pos,
        float* __restrict__ h) {
    int idx = blockIdx.x*256 + threadIdx.x;     // NTOK*D_MODEL
    int d   = idx & (D_MODEL-1);
    int tok = idx >> 9;
    int s   = tok & (SEQ-1);
    int v   = x[tok];
    h[idx] = emb[v*D_MODEL + d] + pos[s*D_MODEL + d];
}

// ---------------- GEMM: C[M,N](bf16) = A[M,K] * B[N,K]^T, B in f32 ----------------
// 64x64 tile, 4 waves (2x2), each wave 32x32 via 2x2 mfma_f32_16x16x32_bf16.
template<bool AF32>
__global__ __launch_bounds__(256) void k_gemm_bt(const void* __restrict__ Ain,
        const float* __restrict__ Bf, bf16* __restrict__ C, int M, int N, int K)
{
    constexpr int BM=64, BN=64, BK=64, LDK=72;   // +8 bf16 pad -> 2-way (free)
    __shared__ __align__(16) bf16 As[BM*LDK];
    __shared__ __align__(16) bf16 Bs[BN*LDK];
    const int t    = threadIdx.x;
    const int m0   = blockIdx.y * BM;
    const int n0   = blockIdx.x * BN;
    const int w    = t >> 6, lane = t & 63;
    const int wm   = (w >> 1)*32, wn = (w & 1)*32;
    const int lr   = lane & 15,  lg = lane >> 4;
    const int srow = t >> 2,     scol = (t & 3) * 16;

    f32x4 acc[2][2] = {};

    for (int kk = 0; kk < K; kk += BK) {
        // stage A (convert f32->bf16 if needed)
        if constexpr (AF32) {
            const float* ga = (const float*)Ain + (size_t)(m0+srow)*K + kk + scol;
            bf16 ta[16];
            #pragma unroll
            for (int e=0;e<16;e+=4) {
                float4 f = *(const float4*)(ga+e);
                ta[e]=f2b(f.x); ta[e+1]=f2b(f.y); ta[e+2]=f2b(f.z); ta[e+3]=f2b(f.w);
            }
            *(uint4*)&As[srow*LDK+scol]   = *(uint4*)&ta[0];
            *(uint4*)&As[srow*LDK+scol+8] = *(uint4*)&ta[8];
        } else {
            const bf16* ga = (const bf16*)Ain + (size_t)(m0+srow)*K + kk + scol;
            *(uint4*)&As[srow*LDK+scol]   = *(const uint4*)ga;
            *(uint4*)&As[srow*LDK+scol+8] = *(const uint4*)(ga+8);
        }
        // stage B (always f32 weights), tail rows -> 0
        {
            int brow = n0 + srow;
            bf16 tb[16];
            if (brow < N) {
                const float* gb = Bf + (size_t)brow*K + kk + scol;
                #pragma unroll
                for (int e=0;e<16;e+=4) {
                    float4 f = *(const float4*)(gb+e);
                    tb[e]=f2b(f.x); tb[e+1]=f2b(f.y); tb[e+2]=f2b(f.z); tb[e+3]=f2b(f.w);
                }
            } else {
                #pragma unroll
                for (int e=0;e<16;e++) tb[e] = f2b(0.f);
            }
            *(uint4*)&Bs[srow*LDK+scol]   = *(uint4*)&tb[0];
            *(uint4*)&Bs[srow*LDK+scol+8] = *(uint4*)&tb[8];
        }
        __syncthreads();
        #pragma unroll
        for (int ks = 0; ks < BK; ks += 32) {
            bf16x8 a0 = *(const bf16x8*)&As[(wm   +lr)*LDK + ks + lg*8];
            bf16x8 a1 = *(const bf16x8*)&As[(wm+16+lr)*LDK + ks + lg*8];
            bf16x8 b0 = *(const bf16x8*)&Bs[(wn   +lr)*LDK + ks + lg*8];
            bf16x8 b1 = *(const bf16x8*)&Bs[(wn+16+lr)*LDK + ks + lg*8];
            acc[0][0] = __builtin_amdgcn_mfma_f32_16x16x32_bf16(a0,b0,acc[0][0],0,0,0);
            acc[0][1] = __builtin_amdgcn_mfma_f32_16x16x32_bf16(a0,b1,acc[0][1],0,0,0);
            acc[1][0] = __builtin_amdgcn_mfma_f32_16x16x32_bf16(a1,b0,acc[1][0],0,0,0);
            acc[1][1] = __builtin_amdgcn_mfma_f32_16x16x32_bf16(a1,b1,acc[1][1],0,0,0);
        }
        __syncthreads();
    }
    // C/D layout (m89/m91): col = lane&15, row = (lane>>4)*4 + reg
    #pragma unroll
    for (int mi=0;mi<2;mi++)
    #pragma unroll
    for (int ni=0;ni<2;ni++) {
        int gcol = n0 + wn + ni*16 + lr;
        if (gcol >= N) continue;
        #pragma unroll
        for (int r=0;r<4;r++) {
            int grow = m0 + wm + mi*16 + lg*4 + r;
            C[(size_t)grow*N + gcol] = f2b(acc[mi][ni][r]);
        }
    }
}

// ---------------- depthwise causal conv (k=4) + silu (chunk-local) ----------------
__global__ __launch_bounds__(256) void k_conv(const bf16* __restrict__ zx,
        const float* __restrict__ cw, const float* __restrict__ cb,
        bf16* __restrict__ out) {
    int idx = blockIdx.x*256 + threadIdx.x;     // CT*CONV_DIM
    int c   = idx % CONV_DIM;
    int tok = idx / CONV_DIM;
    int s   = tok & (SEQ-1);                    // chunks are whole batches
    const bf16* base = zx + (size_t)tok*D_IN_PROJ + D_INNER + c;
    float acc = cb[c];
    #pragma unroll
    for (int k=0;k<4;k++) {
        int off = k - 3;
        if (s + off >= 0) acc += b2f(base[(ptrdiff_t)off*D_IN_PROJ]) * cw[c*4+k];
    }
    out[(size_t)tok*CONV_DIM + c] = f2b(acc / (1.f + __expf(-acc)));
}

// ---------------- dt = softplus(dt_raw+bias); cum = cumsum(dt*A) (chunk-local) ----------------
__global__ __launch_bounds__(256) void k_dtcum(const bf16* __restrict__ zx,
        const float* __restrict__ dt_bias, const float* __restrict__ A_log,
        float* __restrict__ dt, float* __restrict__ cum, int count) {
    int idx = blockIdx.x*256 + threadIdx.x;     // CB*NHEADS
    if (idx >= count) return;
    int hh = idx & (NHEADS-1), b = idx >> 4;
    float bias = dt_bias[hh];
    float A = -__expf(A_log[hh]);
    float c = 0.f;
    for (int s=0;s<SEQ;s++) {
        int tok = b*SEQ + s;
        float xv = b2f(zx[(size_t)tok*D_IN_PROJ + D_INNER + CONV_DIM + hh]) + bias;
        float d = (xv > 20.f) ? xv : log1pf(__expf(xv));
        dt[tok*NHEADS + hh] = d;
        c += d * A;
        cum[tok*NHEADS + hh] = c;
    }
}

// ---------------- SSD core: per (chunk-local) batch ----------------
__global__ __launch_bounds__(256) void k_ssd(const bf16* __restrict__ xbcc,
        const float* __restrict__ dt, const float* __restrict__ cum,
        const float* __restrict__ Dskip, bf16* __restrict__ y) {
    __shared__ float scores[64][66];
    __shared__ float W[64][66];
    __shared__ __align__(16) bf16 xs[64][64];
    __shared__ float cuml[64], dtl[64];
    const int b = blockIdx.x;
    const int t = threadIdx.x;
    const size_t tokbase = (size_t)b*SEQ;
    const int lane = t & 63, lr = lane & 15, lg = lane >> 4;

    // ---- scores via MFMA: wave w handles rows [w*16, w*16+16) ----
    {
        int i0 = (t>>6)*16;
        f32x4 sacc[4] = {};
        const bf16* Cbase = xbcc + tokbase*CONV_DIM + D_INNER + D_STATE;
        const bf16* Bbase = xbcc + tokbase*CONV_DIM + D_INNER;
        #pragma unroll
        for (int ks = 0; ks < D_STATE; ks += 32) {
            bf16x8 af = *(const bf16x8*)(Cbase + (size_t)(i0+lr)*CONV_DIM + ks + lg*8);
            #pragma unroll
            for (int jt = 0; jt < 4; jt++) {
                bf16x8 bfr = *(const bf16x8*)(Bbase + (size_t)(jt*16+lr)*CONV_DIM + ks + lg*8);
                sacc[jt] = __builtin_amdgcn_mfma_f32_16x16x32_bf16(af, bfr, sacc[jt], 0,0,0);
            }
        }
        #pragma unroll
        for (int jt=0;jt<4;jt++)
            #pragma unroll
            for (int r=0;r<4;r++)
                scores[i0 + lg*4 + r][jt*16 + lr] = sacc[jt][r];
    }

    for (int hh = 0; hh < NHEADS; hh++) {
        __syncthreads();    // scores ready (hh=0) / previous head done with W,xs
        if (t < 64) {
            cuml[t] = cum[(tokbase + t)*NHEADS + hh];
            dtl[t]  = dt [(tokbase + t)*NHEADS + hh];
        }
        for (int ch = t; ch < 64*8; ch += 256) {     // stage xs (64x64 bf16)
            int r = ch >> 3, c = (ch & 7)*8;
            *(uint4*)&xs[r][c] = *(const uint4*)(xbcc + (tokbase + r)*CONV_DIM + hh*HEADDIM + c);
        }
        __syncthreads();
        for (int pi = t; pi < 4096; pi += 256) {
            int i = pi >> 6, j = pi & 63;
            W[i][j] = (j <= i) ? scores[i][j] * __expf(cuml[i]-cuml[j]) * dtl[j] : 0.f;
        }
        __syncthreads();
        {
            int i = t >> 2, pg = (t & 3) * 16;
            float acc[16];
            #pragma unroll
            for (int e=0;e<16;e++) acc[e]=0.f;
            for (int j = 0; j <= i; j++) {
                float wv = W[i][j];
                const unsigned* xp = (const unsigned*)&xs[j][pg];
                #pragma unroll
                for (int e=0;e<8;e++) {
                    unsigned u = xp[e];
                    acc[2*e]   += wv * bflo(u);
                    acc[2*e+1] += wv * bfhi(u);
                }
            }
            float dsk = Dskip[hh];
            const unsigned* xi = (const unsigned*)&xs[i][pg];
            bf16 outv[16];
            #pragma unroll
            for (int e=0;e<8;e++) {
                unsigned u = xi[e];
                outv[2*e]   = f2b(acc[2*e]   + dsk*bflo(u));
                outv[2*e+1] = f2b(acc[2*e+1] + dsk*bfhi(u));
            }
            bf16* dst = y + (tokbase + i)*D_INNER + hh*HEADDIM + pg;
            *(uint4*)dst     = *(uint4*)&outv[0];
            *(uint4*)(dst+8) = *(uint4*)&outv[8];
        }
    }
}

// ---------------- y = y*silu(z); RMS-norm * norm_w (in place, bf16, chunk-local) ----------------
__global__ __launch_bounds__(256) void k_gaterms(bf16* __restrict__ y,
        const bf16* __restrict__ zx, const float* __restrict__ nw) {
    int tok = blockIdx.x, t = threadIdx.x;
    __shared__ float red[4];
    int d = t*4;
    uint2 yv = *(const uint2*)(y  + (size_t)tok*D_INNER   + d);
    uint2 zv = *(const uint2*)(zx + (size_t)tok*D_IN_PROJ + d);
    const unsigned* yu = (const unsigned*)&yv;
    const unsigned* zu = (const unsigned*)&zv;
    float g[4]; float ss = 0.f;
    #pragma unroll
    for (int e=0;e<2;e++) {
        float y0 = bflo(yu[e]), y1 = bfhi(yu[e]);
        float z0 = bflo(zu[e]), z1 = bfhi(zu[e]);
        float g0 = y0 * z0 / (1.f + __expf(-z0));
        float g1 = y1 * z1 / (1.f + __expf(-z1));
        g[2*e] = g0; g[2*e+1] = g1;
        ss += g0*g0 + g1*g1;
    }
    for (int o=32;o>0;o>>=1) ss += __shfl_down(ss, o);
    if ((t & 63) == 0) red[t>>6] = ss;
    __syncthreads();
    float tot = red[0]+red[1]+red[2]+red[3];
    float scale = rsqrtf(tot/(float)D_INNER + EPS);
    bf16 outv[4];
    #pragma unroll
    for (int e=0;e<4;e++) outv[e] = f2b(g[e] * scale * nw[d+e]);
    *(uint2*)(y + (size_t)tok*D_INNER + d) = *(uint2*)&outv[0];
}

// ---------------- h += layernorm(tmp)*g + b (h pre-offset to chunk) ----------------
__global__ __launch_bounds__(256) void k_resln(float* __restrict__ h,
        const bf16* __restrict__ tmp, const float* __restrict__ g,
        const float* __restrict__ bb) {
    int tok = blockIdx.x, t = threadIdx.x;
    __shared__ float redS[4], redQ[4];
    int d = t*2;
    unsigned u = *(const unsigned*)(tmp + (size_t)tok*D_MODEL + d);
    float v0 = bflo(u), v1 = bfhi(u);
    float s = v0+v1, q = v0*v0+v1*v1;
    for (int o=32;o>0;o>>=1){ s += __shfl_down(s,o); q += __shfl_down(q,o); }
    if ((t&63)==0){ redS[t>>6]=s; redQ[t>>6]=q; }
    __syncthreads();
    float S = redS[0]+redS[1]+redS[2]+redS[3];
    float Q = redQ[0]+redQ[1]+redQ[2]+redQ[3];
    float mu  = S/(float)D_MODEL;
    float var = Q/(float)D_MODEL - mu*mu;
    float inv = rsqrtf(var + EPS);
    size_t base = (size_t)tok*D_MODEL + d;
    h[base]   += (v0-mu)*inv*g[d]   + bb[d];
    h[base+1] += (v1-mu)*inv*g[d+1] + bb[d+1];
}

// ---------------- masked mean-pool over s ----------------
__global__ __launch_bounds__(256) void k_pool(const float* __restrict__ h,
        float* __restrict__ pooled) {
    int b = blockIdx.x, t = threadIdx.x;
    __shared__ float ps[64][4];
    __shared__ float pm[64];
    __shared__ float cntS;
    {
        int s = t >> 2, q = t & 3;
        const float4* row = (const float4*)(h + ((size_t)b*SEQ + s)*D_MODEL + q*128);
        float acc = 0;
        #pragma unroll 8
        for (int e=0;e<32;e++) { float4 f = row[e]; acc += f.x+f.y+f.z+f.w; }
        ps[s][q] = acc;
    }
    __syncthreads();
    if (t < 64) pm[t] = (ps[t][0]+ps[t][1]+ps[t][2]+ps[t][3]) != 0.f ? 1.f : 0.f;
    __syncthreads();
    if (t == 0) { float c=0; for (int s2=0;s2<64;s2++) c+=pm[s2]; cntS = fmaxf(c,1.f); }
    __syncthreads();
    float cnt = cntS;
    #pragma unroll
    for (int rep=0;rep<2;rep++) {
        int d = t + rep*256;
        float acc = 0;
        for (int s2=0;s2<64;s2++) acc += h[((size_t)b*SEQ+s2)*D_MODEL + d] * pm[s2];
        pooled[(size_t)b*D_MODEL + d] = acc / cnt;
    }
}

// ---------------- fc1(relu) + fc2 ----------------
__global__ __launch_bounds__(128) void k_fc(const float* __restrict__ pooled,
        const float* __restrict__ w1, const float* __restrict__ b1,
        const float* __restrict__ w2, const float* __restrict__ b2,
        float* __restrict__ out) {
    int b = blockIdx.x, j = threadIdx.x;
    __shared__ float hid[FC_HID];
    const float* p  = pooled + (size_t)b*D_MODEL;
    const float* wr = w1 + (size_t)j*D_MODEL;
    float acc = b1[j];
    for (int d=0; d<D_MODEL; d+=4)
        acc += p[d]*wr[d] + p[d+1]*wr[d+1] + p[d+2]*wr[d+2] + p[d+3]*wr[d+3];
    hid[j] = fmaxf(acc, 0.f);
    __syncthreads();
    if (j < 2) {
        float o = b2[j];
        for (int k=0;k<FC_HID;k++) o += hid[k]*w2[j*FC_HID+k];
        out[b*2 + j] = o;
    }
}

extern "C" void kernel_launch(void* const* d_in, const int* in_sizes, int n_in,
                              void* d_out, int out_size, void* d_ws, size_t ws_size,
                              hipStream_t stream) {
    (void)in_sizes; (void)n_in; (void)out_size;
    const int*   x        = (const int*)  d_in[0];
    const float* emb      = (const float*)d_in[1];
    const float* pos      = (const float*)d_in[2];
    const float* in_proj  = (const float*)d_in[3];
    const float* conv_w   = (const float*)d_in[4];
    const float* conv_b   = (const float*)d_in[5];
    const float* dt_bias  = (const float*)d_in[6];
    const float* A_log    = (const float*)d_in[7];
    const float* D_skip   = (const float*)d_in[8];
    const float* norm_w   = (const float*)d_in[9];
    const float* out_proj = (const float*)d_in[10];
    const float* ln_g     = (const float*)d_in[11];
    const float* ln_b     = (const float*)d_in[12];
    const float* fc1_w    = (const float*)d_in[13];
    const float* fc1_b    = (const float*)d_in[14];
    const float* fc2_w    = (const float*)d_in[15];
    const float* fc2_b    = (const float*)d_in[16];
    float* out = (float*)d_out;

    // ---- adaptive chunking over batch: transient buffers sized for CB batches ----
    const size_t H_BYTES = (size_t)NTOK * D_MODEL * 4;          // 64 MB, persistent
    const size_t PER_TOK = (size_t)D_IN_PROJ*2 + (size_t)CONV_DIM*2
                         + (size_t)D_INNER*2 + 2*NHEADS*4;      // 9376 B
    int CB = BATCH;
    while (CB > 8 && H_BYTES + (size_t)CB*SEQ*PER_TOK > ws_size) CB >>= 1;
    const int CT = CB * SEQ;            // tokens per chunk
    const int NC = BATCH / CB;          // number of chunks

    char* ws = (char*)d_ws;
    float* h    = (float*)(ws);
    char*  tr   = ws + H_BYTES;                        // transient region
    bf16*  zx   = (bf16*) (tr);                                        // CT*2320
    bf16*  xbcc = (bf16*) (tr + (size_t)CT*D_IN_PROJ*2);               // CT*1280
    bf16*  ybuf = (bf16*) (tr + (size_t)CT*(D_IN_PROJ+CONV_DIM)*2);    // CT*1024
    float* dt   = (float*)(tr + (size_t)CT*(D_IN_PROJ+CONV_DIM+D_INNER)*2);
    float* cum  = dt + (size_t)CT*NHEADS;
    bf16*  tmp  = xbcc;                 // alias: xbcc dead after k_ssd
    float* pooled = (float*)tr;         // alias transients: used after layers

    k_embed<<<(NTOK*D_MODEL)/256, 256, 0, stream>>>(x, emb, pos, h);

    for (int l = 0; l < NLAYERS; l++) {
        const float* ipw = in_proj + (size_t)l*D_IN_PROJ*D_MODEL;
        const float* opw = out_proj + (size_t)l*D_MODEL*D_INNER;
        for (int c = 0; c < NC; c++) {
            const int tok0 = c * CT;
            float* hc = h + (size_t)tok0 * D_MODEL;
            dim3 g1((D_IN_PROJ+63)/64, CT/64);
            k_gemm_bt<true><<<g1, 256, 0, stream>>>(hc, ipw, zx, CT, D_IN_PROJ, D_MODEL);
            k_conv<<<(CT*CONV_DIM)/256, 256, 0, stream>>>(zx,
                    conv_w + (size_t)l*CONV_DIM*D_CONV, conv_b + (size_t)l*CONV_DIM, xbcc);
            int cnt = CB * NHEADS;
            k_dtcum<<<(cnt+255)/256, 256, 0, stream>>>(zx, dt_bias + l*NHEADS,
                    A_log + l*NHEADS, dt, cum, cnt);
            k_ssd<<<CB, 256, 0, stream>>>(xbcc, dt, cum, D_skip + l*NHEADS, ybuf);
            k_gaterms<<<CT, 256, 0, stream>>>(ybuf, zx, norm_w + (size_t)l*D_INNER);
            dim3 g2(D_MODEL/64, CT/64);
            k_gemm_bt<false><<<g2, 256, 0, stream>>>(ybuf, opw, tmp, CT, D_MODEL, D_INNER);
            k_resln<<<CT, 256, 0, stream>>>(hc, tmp, ln_g + l*D_MODEL, ln_b + l*D_MODEL);
        }
    }

    k_pool<<<BATCH, 256, 0, stream>>>(h, pooled);
    k_fc<<<BATCH, FC_HID, 0, stream>>>(pooled, fc1_w, fc1_b, fc2_w, fc2_b, out);
}

// Round 3
// 1742.760 us; speedup vs baseline: 1.2402x; 1.2402x over previous
//
#include <hip/hip_runtime.h>
#include <hip/hip_bf16.h>

// ---- problem constants ----
#define D_MODEL   512
#define D_STATE   128
#define D_CONV    4
#define HEADDIM   64
#define NLAYERS   2
#define D_INNER   1024
#define NHEADS    16
#define CONV_DIM  1280          // D_INNER + 2*D_STATE
#define D_IN_PROJ 2320          // 2*D_INNER + 2*D_STATE + NHEADS
#define NPAD      2432          // D_IN_PROJ padded to 128
#define SEQ       64
#define BATCH     512
#define NTOK      (BATCH*SEQ)   // 32768
#define FC_HID    128
#define EPS       1e-5f

using bf16 = __hip_bfloat16;
typedef __bf16 bf16x8 __attribute__((ext_vector_type(8)));
typedef float  f32x4  __attribute__((ext_vector_type(4)));

__device__ __forceinline__ float b2f(bf16 v)  { return __bfloat162float(v); }
__device__ __forceinline__ bf16  f2b(float v) { return __float2bfloat16(v); }
__device__ __forceinline__ float bflo(unsigned u){ return __builtin_bit_cast(float, u << 16); }
__device__ __forceinline__ float bfhi(unsigned u){ return __builtin_bit_cast(float, u & 0xffff0000u); }

__device__ __forceinline__ void gl_lds16(const void* g, void* l) {
    __builtin_amdgcn_global_load_lds((const __attribute__((address_space(1))) void*)g,
                                     (__attribute__((address_space(3))) void*)l, 16, 0, 0);
}

// ---------------- embedding: h = emb[x]+pos (f32) and bf16 shadow hb ----------------
__global__ __launch_bounds__(256) void k_embed(const int* __restrict__ x,
        const float* __restrict__ emb, const float* __restrict__ pos,
        float* __restrict__ h, bf16* __restrict__ hb) {
    int idx = blockIdx.x*256 + threadIdx.x;     // NTOK*D_MODEL
    int d   = idx & (D_MODEL-1);
    int tok = idx >> 9;
    int s   = tok & (SEQ-1);
    int v   = x[tok];
    float r = emb[v*D_MODEL + d] + pos[s*D_MODEL + d];
    h[idx]  = r;
    hb[idx] = f2b(r);
}

// ---------------- weight convert f32 -> bf16, zero-padded rows ----------------
__global__ __launch_bounds__(256) void k_cvtw(const float* __restrict__ src,
        bf16* __restrict__ dst, int R, int Kc, int total8) {
    int idx = blockIdx.x*256 + threadIdx.x;
    if (idx >= total8) return;
    int e0 = idx*8;
    int r = e0 / Kc, c = e0 % Kc;
    bf16 tb[8];
    if (r < R) {
        float4 f0 = *(const float4*)(src + (size_t)r*Kc + c);
        float4 f1 = *(const float4*)(src + (size_t)r*Kc + c + 4);
        tb[0]=f2b(f0.x); tb[1]=f2b(f0.y); tb[2]=f2b(f0.z); tb[3]=f2b(f0.w);
        tb[4]=f2b(f1.x); tb[5]=f2b(f1.y); tb[6]=f2b(f1.z); tb[7]=f2b(f1.w);
    } else {
        #pragma unroll
        for (int e=0;e<8;e++) tb[e] = f2b(0.f);
    }
    *(uint4*)(dst + (size_t)r*Kc + c) = *(uint4*)&tb[0];
}

// ---------------- GEMM 128x128 (m97-style): C[M,Nout] = A[M,K] * B[Npad,K]^T ----------------
// A,B bf16 row-major stride K. 256 thr = 4 waves (2x2), wave = 64x64 (4x4 frags).
// global_load_lds staging, XCD-bijective swizzle, LDS-repacked coalesced C store.
__global__ __launch_bounds__(256) void k_gemm128(const bf16* __restrict__ A,
        const bf16* __restrict__ B, bf16* __restrict__ C,
        int Nout, int K, int nbx)
{
    __shared__ __align__(16) char ldsbuf[128*136*2];   // 34816 B
    bf16* As = (bf16*)ldsbuf;                          // [128][64]
    bf16* Bs = (bf16*)(ldsbuf + 16384);                // [128][64]
    bf16* Cs = (bf16*)ldsbuf;                          // [128][136] (repack)

    // bijective XCD swizzle (m204)
    const int nwg = gridDim.x;
    const int q = nwg >> 3, r = nwg & 7;
    const int xcd = blockIdx.x & 7, loc = blockIdx.x >> 3;
    const int wg = ((xcd < r) ? xcd*(q+1) : r*(q+1) + (xcd-r)*q) + loc;
    const int m0 = (wg / nbx) * 128;
    const int n0 = (wg % nbx) * 128;

    const int t = threadIdx.x;
    const int wid = t >> 6, lane = t & 63;
    const int lr = lane & 15, lg = lane >> 4;
    const int wm = (wid >> 1)*64, wn = (wid & 1)*64;
    const int srow = wid*32, lrow = lane >> 3, lcol = (lane & 7)*8;

    f32x4 acc[4][4] = {};

    for (int kk = 0; kk < K; kk += 64) {
        #pragma unroll
        for (int c = 0; c < 4; c++) {
            gl_lds16(A + (size_t)(m0+srow+c*8+lrow)*K + kk + lcol, &As[(srow + c*8)*64]);
            gl_lds16(B + (size_t)(n0+srow+c*8+lrow)*K + kk + lcol, &Bs[(srow + c*8)*64]);
        }
        __syncthreads();
        #pragma unroll
        for (int ks = 0; ks < 64; ks += 32) {
            bf16x8 a[4], b[4];
            #pragma unroll
            for (int mi=0;mi<4;mi++) a[mi] = *(const bf16x8*)&As[(wm+mi*16+lr)*64 + ks + lg*8];
            #pragma unroll
            for (int ni=0;ni<4;ni++) b[ni] = *(const bf16x8*)&Bs[(wn+ni*16+lr)*64 + ks + lg*8];
            #pragma unroll
            for (int mi=0;mi<4;mi++)
                #pragma unroll
                for (int ni=0;ni<4;ni++)
                    acc[mi][ni] = __builtin_amdgcn_mfma_f32_16x16x32_bf16(a[mi], b[ni], acc[mi][ni], 0,0,0);
        }
        __syncthreads();
    }

    // repack C tile into LDS (bank-safe: stride 136)
    #pragma unroll
    for (int mi=0;mi<4;mi++)
        #pragma unroll
        for (int ni=0;ni<4;ni++)
            #pragma unroll
            for (int rr=0;rr<4;rr++)
                Cs[(wm+mi*16+lg*4+rr)*136 + wn+ni*16+lr] = f2b(acc[mi][ni][rr]);
    __syncthreads();
    // cooperative coalesced store: 2048 chunks of 8 bf16
    #pragma unroll
    for (int it = 0; it < 8; it++) {
        int chunk = it*256 + t;
        int row = chunk >> 4, c8 = (chunk & 15) << 3;
        int gcol = n0 + c8;
        if (gcol < Nout)
            *(uint4*)(C + (size_t)(m0+row)*Nout + gcol) = *(const uint4*)&Cs[row*136 + c8];
    }
}

// ---------------- depthwise causal conv (k=4) + silu, 8 ch/thread ----------------
__global__ __launch_bounds__(256) void k_conv(const bf16* __restrict__ zx,
        const float* __restrict__ cw, const float* __restrict__ cb,
        bf16* __restrict__ out) {
    int idx = blockIdx.x*256 + threadIdx.x;     // CT*160
    int c8  = (idx % 160)*8;
    int tok = idx / 160;
    int s   = tok & (SEQ-1);
    const bf16* base = zx + (size_t)tok*D_IN_PROJ + D_INNER + c8;
    float acc[8];
    {
        const float4* cbp = (const float4*)(cb + c8);
        float4 b0 = cbp[0], b1 = cbp[1];
        acc[0]=b0.x; acc[1]=b0.y; acc[2]=b0.z; acc[3]=b0.w;
        acc[4]=b1.x; acc[5]=b1.y; acc[6]=b1.z; acc[7]=b1.w;
    }
    #pragma unroll
    for (int k=0;k<4;k++) {
        int off = k - 3;
        if (s + off >= 0) {
            uint4 xv = *(const uint4*)(base + (ptrdiff_t)off*D_IN_PROJ);
            const unsigned* xu = (const unsigned*)&xv;
            #pragma unroll
            for (int e=0;e<4;e++) {
                unsigned u = xu[e];
                acc[2*e]   += bflo(u) * cw[(c8+2*e  )*4 + k];
                acc[2*e+1] += bfhi(u) * cw[(c8+2*e+1)*4 + k];
            }
        }
    }
    bf16 outv[8];
    #pragma unroll
    for (int e=0;e<8;e++) outv[e] = f2b(acc[e] / (1.f + __expf(-acc[e])));
    *(uint4*)(out + (size_t)tok*CONV_DIM + c8) = *(uint4*)&outv[0];
}

// ---------------- dt/cum via wave prefix scan; layout [head][tok] ----------------
__global__ __launch_bounds__(256) void k_dtcum(const bf16* __restrict__ zx,
        const float* __restrict__ dt_bias, const float* __restrict__ A_log,
        float* __restrict__ dt, float* __restrict__ cum, int npairs, int ctok) {
    int pair = blockIdx.x*4 + (threadIdx.x >> 6);
    if (pair >= npairs) return;
    int lane = threadIdx.x & 63;
    int hh = pair & (NHEADS-1), b = pair >> 4;
    int tok = b*SEQ + lane;
    float xv = b2f(zx[(size_t)tok*D_IN_PROJ + D_INNER + CONV_DIM + hh]) + dt_bias[hh];
    float d = (xv > 20.f) ? xv : log1pf(__expf(xv));
    float A = -__expf(A_log[hh]);
    float c = d * A;
    #pragma unroll
    for (int o=1;o<64;o<<=1) { float v = __shfl_up(c, o); if (lane >= o) c += v; }
    dt [(size_t)hh*ctok + tok] = d;
    cum[(size_t)hh*ctok + tok] = c;
}

// ---------------- SSD core: per (chunk-local) batch ----------------
__global__ __launch_bounds__(256) void k_ssd(const bf16* __restrict__ xbcc,
        const float* __restrict__ dt, const float* __restrict__ cum,
        const float* __restrict__ Dskip, bf16* __restrict__ y, int ctok) {
    __shared__ float scores[64][66];
    __shared__ float W[64][66];
    __shared__ __align__(16) bf16 xs[64][64];
    __shared__ float cuml[64], dtl[64];
    const int b = blockIdx.x;
    const int t = threadIdx.x;
    const size_t tokbase = (size_t)b*SEQ;
    const int lane = t & 63, lr = lane & 15, lg = lane >> 4;

    {   // scores via MFMA: wave w handles rows [w*16, w*16+16)
        int i0 = (t>>6)*16;
        f32x4 sacc[4] = {};
        const bf16* Cbase = xbcc + tokbase*CONV_DIM + D_INNER + D_STATE;
        const bf16* Bbase = xbcc + tokbase*CONV_DIM + D_INNER;
        #pragma unroll
        for (int ks = 0; ks < D_STATE; ks += 32) {
            bf16x8 af = *(const bf16x8*)(Cbase + (size_t)(i0+lr)*CONV_DIM + ks + lg*8);
            #pragma unroll
            for (int jt = 0; jt < 4; jt++) {
                bf16x8 bfr = *(const bf16x8*)(Bbase + (size_t)(jt*16+lr)*CONV_DIM + ks + lg*8);
                sacc[jt] = __builtin_amdgcn_mfma_f32_16x16x32_bf16(af, bfr, sacc[jt], 0,0,0);
            }
        }
        #pragma unroll
        for (int jt=0;jt<4;jt++)
            #pragma unroll
            for (int r=0;r<4;r++)
                scores[i0 + lg*4 + r][jt*16 + lr] = sacc[jt][r];
    }

    for (int hh = 0; hh < NHEADS; hh++) {
        __syncthreads();
        if (t < 64) {
            cuml[t] = cum[(size_t)hh*ctok + tokbase + t];
            dtl[t]  = dt [(size_t)hh*ctok + tokbase + t];
        }
        for (int ch = t; ch < 64*8; ch += 256) {
            int r = ch >> 3, c = (ch & 7)*8;
            *(uint4*)&xs[r][c] = *(const uint4*)(xbcc + (tokbase + r)*CONV_DIM + hh*HEADDIM + c);
        }
        __syncthreads();
        for (int pi = t; pi < 4096; pi += 256) {
            int i = pi >> 6, j = pi & 63;
            W[i][j] = (j <= i) ? scores[i][j] * __expf(cuml[i]-cuml[j]) * dtl[j] : 0.f;
        }
        __syncthreads();
        {
            int i = t >> 2, pg = (t & 3) * 16;
            float acc[16];
            #pragma unroll
            for (int e=0;e<16;e++) acc[e]=0.f;
            for (int j = 0; j <= i; j++) {
                float wv = W[i][j];
                const unsigned* xp = (const unsigned*)&xs[j][pg];
                #pragma unroll
                for (int e=0;e<8;e++) {
                    unsigned u = xp[e];
                    acc[2*e]   += wv * bflo(u);
                    acc[2*e+1] += wv * bfhi(u);
                }
            }
            float dsk = Dskip[hh];
            const unsigned* xi = (const unsigned*)&xs[i][pg];
            bf16 outv[16];
            #pragma unroll
            for (int e=0;e<8;e++) {
                unsigned u = xi[e];
                outv[2*e]   = f2b(acc[2*e]   + dsk*bflo(u));
                outv[2*e+1] = f2b(acc[2*e+1] + dsk*bfhi(u));
            }
            bf16* dst = y + (tokbase + i)*D_INNER + hh*HEADDIM + pg;
            *(uint4*)dst     = *(uint4*)&outv[0];
            *(uint4*)(dst+8) = *(uint4*)&outv[8];
        }
    }
}

// ---------------- y = y*silu(z); RMS-norm * norm_w (in place, bf16) ----------------
__global__ __launch_bounds__(256) void k_gaterms(bf16* __restrict__ y,
        const bf16* __restrict__ zx, const float* __restrict__ nw) {
    int tok = blockIdx.x, t = threadIdx.x;
    __shared__ float red[4];
    int d = t*4;
    uint2 yv = *(const uint2*)(y  + (size_t)tok*D_INNER   + d);
    uint2 zv = *(const uint2*)(zx + (size_t)tok*D_IN_PROJ + d);
    const unsigned* yu = (const unsigned*)&yv;
    const unsigned* zu = (const unsigned*)&zv;
    float g[4]; float ss = 0.f;
    #pragma unroll
    for (int e=0;e<2;e++) {
        float y0 = bflo(yu[e]), y1 = bfhi(yu[e]);
        float z0 = bflo(zu[e]), z1 = bfhi(zu[e]);
        float g0 = y0 * z0 / (1.f + __expf(-z0));
        float g1 = y1 * z1 / (1.f + __expf(-z1));
        g[2*e] = g0; g[2*e+1] = g1;
        ss += g0*g0 + g1*g1;
    }
    for (int o=32;o>0;o>>=1) ss += __shfl_down(ss, o);
    if ((t & 63) == 0) red[t>>6] = ss;
    __syncthreads();
    float tot = red[0]+red[1]+red[2]+red[3];
    float scale = rsqrtf(tot/(float)D_INNER + EPS);
    bf16 outv[4];
    #pragma unroll
    for (int e=0;e<4;e++) outv[e] = f2b(g[e] * scale * nw[d+e]);
    *(uint2*)(y + (size_t)tok*D_INNER + d) = *(uint2*)&outv[0];
}

// ---------------- h += layernorm(tmp)*g + b; refresh hb ----------------
__global__ __launch_bounds__(256) void k_resln(float* __restrict__ h,
        bf16* __restrict__ hb, const bf16* __restrict__ tmp,
        const float* __restrict__ g, const float* __restrict__ bb) {
    int tok = blockIdx.x, t = threadIdx.x;
    __shared__ float redS[4], redQ[4];
    int d = t*2;
    unsigned u = *(const unsigned*)(tmp + (size_t)tok*D_MODEL + d);
    float v0 = bflo(u), v1 = bfhi(u);
    float s = v0+v1, q = v0*v0+v1*v1;
    for (int o=32;o>0;o>>=1){ s += __shfl_down(s,o); q += __shfl_down(q,o); }
    if ((t&63)==0){ redS[t>>6]=s; redQ[t>>6]=q; }
    __syncthreads();
    float S = redS[0]+redS[1]+redS[2]+redS[3];
    float Q = redQ[0]+redQ[1]+redQ[2]+redQ[3];
    float mu  = S/(float)D_MODEL;
    float var = Q/(float)D_MODEL - mu*mu;
    float inv = rsqrtf(var + EPS);
    size_t base = (size_t)tok*D_MODEL + d;
    float h0 = h[base]   + (v0-mu)*inv*g[d]   + bb[d];
    float h1 = h[base+1] + (v1-mu)*inv*g[d+1] + bb[d+1];
    h[base] = h0; h[base+1] = h1;
    bf16 o2[2] = { f2b(h0), f2b(h1) };
    *(unsigned*)(hb + base) = *(unsigned*)&o2[0];
}

// ---------------- masked mean-pool over s ----------------
__global__ __launch_bounds__(256) void k_pool(const float* __restrict__ h,
        float* __restrict__ pooled) {
    int b = blockIdx.x, t = threadIdx.x;
    __shared__ float ps[64][4];
    __shared__ float pm[64];
    __shared__ float cntS;
    {
        int s = t >> 2, q = t & 3;
        const float4* row = (const float4*)(h + ((size_t)b*SEQ + s)*D_MODEL + q*128);
        float acc = 0;
        #pragma unroll 8
        for (int e=0;e<32;e++) { float4 f = row[e]; acc += f.x+f.y+f.z+f.w; }
        ps[s][q] = acc;
    }
    __syncthreads();
    if (t < 64) pm[t] = (ps[t][0]+ps[t][1]+ps[t][2]+ps[t][3]) != 0.f ? 1.f : 0.f;
    __syncthreads();
    if (t == 0) { float c=0; for (int s2=0;s2<64;s2++) c+=pm[s2]; cntS = fmaxf(c,1.f); }
    __syncthreads();
    float cnt = cntS;
    #pragma unroll
    for (int rep=0;rep<2;rep++) {
        int d = t + rep*256;
        float acc = 0;
        for (int s2=0;s2<64;s2++) acc += h[((size_t)b*SEQ+s2)*D_MODEL + d] * pm[s2];
        pooled[(size_t)b*D_MODEL + d] = acc / cnt;
    }
}

// ---------------- fc1(relu) + fc2 ----------------
__global__ __launch_bounds__(128) void k_fc(const float* __restrict__ pooled,
        const float* __restrict__ w1, const float* __restrict__ b1,
        const float* __restrict__ w2, const float* __restrict__ b2,
        float* __restrict__ out) {
    int b = blockIdx.x, j = threadIdx.x;
    __shared__ float hid[FC_HID];
    const float* p  = pooled + (size_t)b*D_MODEL;
    const float* wr = w1 + (size_t)j*D_MODEL;
    float acc = b1[j];
    for (int d=0; d<D_MODEL; d+=4)
        acc += p[d]*wr[d] + p[d+1]*wr[d+1] + p[d+2]*wr[d+2] + p[d+3]*wr[d+3];
    hid[j] = fmaxf(acc, 0.f);
    __syncthreads();
    if (j < 2) {
        float o = b2[j];
        for (int k=0;k<FC_HID;k++) o += hid[k]*w2[j*FC_HID+k];
        out[b*2 + j] = o;
    }
}

extern "C" void kernel_launch(void* const* d_in, const int* in_sizes, int n_in,
                              void* d_out, int out_size, void* d_ws, size_t ws_size,
                              hipStream_t stream) {
    (void)in_sizes; (void)n_in; (void)out_size;
    const int*   x        = (const int*)  d_in[0];
    const float* emb      = (const float*)d_in[1];
    const float* pos      = (const float*)d_in[2];
    const float* in_proj  = (const float*)d_in[3];
    const float* conv_w   = (const float*)d_in[4];
    const float* conv_b   = (const float*)d_in[5];
    const float* dt_bias  = (const float*)d_in[6];
    const float* A_log    = (const float*)d_in[7];
    const float* D_skip   = (const float*)d_in[8];
    const float* norm_w   = (const float*)d_in[9];
    const float* out_proj = (const float*)d_in[10];
    const float* ln_g     = (const float*)d_in[11];
    const float* ln_b     = (const float*)d_in[12];
    const float* fc1_w    = (const float*)d_in[13];
    const float* fc1_b    = (const float*)d_in[14];
    const float* fc2_w    = (const float*)d_in[15];
    const float* fc2_b    = (const float*)d_in[16];
    float* out = (float*)d_out;

    // ---- persistent region ----
    const size_t H_B   = (size_t)NTOK * D_MODEL * 4;     // 64 MB f32 h
    const size_t HB_B  = (size_t)NTOK * D_MODEL * 2;     // 32 MB bf16 shadow
    const size_t WPI_B = (size_t)NPAD * D_MODEL * 2;     // per layer 2.49 MB
    const size_t WPO_B = (size_t)D_MODEL * D_INNER * 2;  // per layer 1 MB
    const size_t PBASE = H_B + HB_B + NLAYERS*(WPI_B + WPO_B);

    const size_t PER_TOK = (size_t)D_IN_PROJ*2 + (size_t)CONV_DIM*2
                         + (size_t)D_INNER*2 + 2*NHEADS*4;      // 9376 B
    int CB = BATCH;
    while (CB > 8 && PBASE + (size_t)CB*SEQ*PER_TOK > ws_size) CB >>= 1;
    const int CT = CB * SEQ;
    const int NC = BATCH / CB;

    char* ws = (char*)d_ws;
    float* h    = (float*)(ws);
    bf16*  hb   = (bf16*) (ws + H_B);
    bf16*  wpi  = (bf16*) (ws + H_B + HB_B);                   // [NLAYERS][NPAD][512]
    bf16*  wpo  = (bf16*) (ws + H_B + HB_B + NLAYERS*WPI_B);   // [NLAYERS][512][1024]
    char*  tr   = ws + PBASE;
    bf16*  zx   = (bf16*) (tr);                                        // CT*2320
    bf16*  xbcc = (bf16*) (tr + (size_t)CT*D_IN_PROJ*2);               // CT*1280
    bf16*  ybuf = (bf16*) (tr + (size_t)CT*(D_IN_PROJ+CONV_DIM)*2);    // CT*1024
    float* dt   = (float*)(tr + (size_t)CT*(D_IN_PROJ+CONV_DIM+D_INNER)*2);
    float* cum  = dt + (size_t)CT*NHEADS;
    bf16*  tmp  = xbcc;                 // alias: xbcc dead after k_ssd
    float* pooled = (float*)tr;

    // weight conversion (both layers, once per launch)
    for (int l = 0; l < NLAYERS; l++) {
        int t8i = NPAD*D_MODEL/8;
        k_cvtw<<<(t8i+255)/256, 256, 0, stream>>>(in_proj + (size_t)l*D_IN_PROJ*D_MODEL,
                wpi + (size_t)l*NPAD*D_MODEL, D_IN_PROJ, D_MODEL, t8i);
        int t8o = D_MODEL*D_INNER/8;
        k_cvtw<<<(t8o+255)/256, 256, 0, stream>>>(out_proj + (size_t)l*D_MODEL*D_INNER,
                wpo + (size_t)l*D_MODEL*D_INNER, D_MODEL, D_INNER, t8o);
    }

    k_embed<<<(NTOK*D_MODEL)/256, 256, 0, stream>>>(x, emb, pos, h, hb);

    const int NBX_I = NPAD/128;     // 19
    const int NBX_O = D_MODEL/128;  // 4

    for (int l = 0; l < NLAYERS; l++) {
        const bf16* wi = wpi + (size_t)l*NPAD*D_MODEL;
        const bf16* wo = wpo + (size_t)l*D_MODEL*D_INNER;
        for (int c = 0; c < NC; c++) {
            const int tok0 = c * CT;
            float* hc  = h  + (size_t)tok0 * D_MODEL;
            bf16*  hbc = hb + (size_t)tok0 * D_MODEL;
            k_gemm128<<<(CT/128)*NBX_I, 256, 0, stream>>>(hbc, wi, zx, D_IN_PROJ, D_MODEL, NBX_I);
            k_conv<<<(CT*160)/256, 256, 0, stream>>>(zx,
                    conv_w + (size_t)l*CONV_DIM*D_CONV, conv_b + (size_t)l*CONV_DIM, xbcc);
            int npairs = CB * NHEADS;
            k_dtcum<<<(npairs+3)/4, 256, 0, stream>>>(zx, dt_bias + l*NHEADS,
                    A_log + l*NHEADS, dt, cum, npairs, CT);
            k_ssd<<<CB, 256, 0, stream>>>(xbcc, dt, cum, D_skip + l*NHEADS, ybuf, CT);
            k_gaterms<<<CT, 256, 0, stream>>>(ybuf, zx, norm_w + (size_t)l*D_INNER);
            k_gemm128<<<(CT/128)*NBX_O, 256, 0, stream>>>(ybuf, wo, tmp, D_MODEL, D_INNER, NBX_O);
            k_resln<<<CT, 256, 0, stream>>>(hc, hbc, tmp, ln_g + l*D_MODEL, ln_b + l*D_MODEL);
        }
    }

    k_pool<<<BATCH, 256, 0, stream>>>(h, pooled);
    k_fc<<<BATCH, FC_HID, 0, stream>>>(pooled, fc1_w, fc1_b, fc2_w, fc2_b, out);
}

// Round 5
// 1190.468 us; speedup vs baseline: 1.8155x; 1.4639x over previous
//
#include <hip/hip_runtime.h>
#include <hip/hip_bf16.h>

// ---- problem constants ----
#define D_MODEL   512
#define D_STATE   128
#define D_CONV    4
#define HEADDIM   64
#define NLAYERS   2
#define D_INNER   1024
#define NHEADS    16
#define CONV_DIM  1280          // D_INNER + 2*D_STATE
#define D_IN_PROJ 2320          // 2*D_INNER + 2*D_STATE + NHEADS
#define NPAD      2432          // D_IN_PROJ padded to 128
#define SEQ       64
#define BATCH     512
#define NTOK      (BATCH*SEQ)   // 32768
#define FC_HID    128
#define EPS       1e-5f

using bf16 = __hip_bfloat16;
typedef __bf16 bf16x8 __attribute__((ext_vector_type(8)));
typedef float  f32x4  __attribute__((ext_vector_type(4)));

__device__ __forceinline__ float b2f(bf16 v)  { return __bfloat162float(v); }
__device__ __forceinline__ bf16  f2b(float v) { return __float2bfloat16(v); }
__device__ __forceinline__ float bflo(unsigned u){ return __builtin_bit_cast(float, u << 16); }
__device__ __forceinline__ float bfhi(unsigned u){ return __builtin_bit_cast(float, u & 0xffff0000u); }

__device__ __forceinline__ void gl_lds16(const void* g, void* l) {
    __builtin_amdgcn_global_load_lds((const __attribute__((address_space(1))) void*)g,
                                     (__attribute__((address_space(3))) void*)l, 16, 0, 0);
}

// ---------------- embedding: h = emb[x]+pos (f32) and bf16 shadow hb ----------------
__global__ __launch_bounds__(256) void k_embed(const int* __restrict__ x,
        const float* __restrict__ emb, const float* __restrict__ pos,
        float* __restrict__ h, bf16* __restrict__ hb) {
    int idx = blockIdx.x*256 + threadIdx.x;     // NTOK*D_MODEL
    int d   = idx & (D_MODEL-1);
    int tok = idx >> 9;
    int s   = tok & (SEQ-1);
    int v   = x[tok];
    float r = emb[v*D_MODEL + d] + pos[s*D_MODEL + d];
    h[idx]  = r;
    hb[idx] = f2b(r);
}

// ---------------- weight convert f32 -> bf16, zero-padded rows ----------------
__global__ __launch_bounds__(256) void k_cvtw(const float* __restrict__ src,
        bf16* __restrict__ dst, int R, int Kc, int total8) {
    int idx = blockIdx.x*256 + threadIdx.x;
    if (idx >= total8) return;
    int e0 = idx*8;
    int r = e0 / Kc, c = e0 % Kc;
    bf16 tb[8];
    if (r < R) {
        float4 f0 = *(const float4*)(src + (size_t)r*Kc + c);
        float4 f1 = *(const float4*)(src + (size_t)r*Kc + c + 4);
        tb[0]=f2b(f0.x); tb[1]=f2b(f0.y); tb[2]=f2b(f0.z); tb[3]=f2b(f0.w);
        tb[4]=f2b(f1.x); tb[5]=f2b(f1.y); tb[6]=f2b(f1.z); tb[7]=f2b(f1.w);
    } else {
        #pragma unroll
        for (int e=0;e<8;e++) tb[e] = f2b(0.f);
    }
    *(uint4*)(dst + (size_t)r*Kc + c) = *(uint4*)&tb[0];
}

// ---------------- GEMM 128x128: C = A[M,K] * B[Npad,K]^T (bf16 in, bf16 out) ----------------
// FUSE=0: plain store to C[M][Nout].
// FUSE=1: in_proj epilogue — n0<1024: raw z -> C (zbuf, stride 1024);
//         1024<=n0<2304: depthwise causal conv(k=4)+silu -> xbcc (stride 1280);
//         n0==2304: softplus+cumsum scan -> dt, cum ([head][ctok] f32).
template<int FUSE>
__global__ __launch_bounds__(256) void k_gemm128(const bf16* __restrict__ A,
        const bf16* __restrict__ B, bf16* __restrict__ C,
        bf16* __restrict__ xbcc, float* __restrict__ dt, float* __restrict__ cum,
        const float* __restrict__ cw, const float* __restrict__ cb,
        const float* __restrict__ dt_bias, const float* __restrict__ A_log,
        int Nout, int K, int nbx, int ctok)
{
    __shared__ __align__(16) char ldsbuf[128*136*2];   // 34816 B
    bf16* As = (bf16*)ldsbuf;                          // [128][64]
    bf16* Bs = (bf16*)(ldsbuf + 16384);                // [128][64]
    bf16* Cs = (bf16*)ldsbuf;                          // [128][136] (repack)

    // bijective XCD swizzle (m204)
    const int nwg = gridDim.x;
    const int q = nwg >> 3, r = nwg & 7;
    const int xcd = blockIdx.x & 7, loc = blockIdx.x >> 3;
    const int wg = ((xcd < r) ? xcd*(q+1) : r*(q+1) + (xcd-r)*q) + loc;
    const int m0 = (wg / nbx) * 128;
    const int n0 = (wg % nbx) * 128;

    const int t = threadIdx.x;
    const int wid = t >> 6, lane = t & 63;
    const int lr = lane & 15, lg = lane >> 4;
    const int wm = (wid >> 1)*64, wn = (wid & 1)*64;
    const int srow = wid*32, lrow = lane >> 3, lcol = (lane & 7)*8;

    f32x4 acc[4][4] = {};

    for (int kk = 0; kk < K; kk += 64) {
        #pragma unroll
        for (int c = 0; c < 4; c++) {
            gl_lds16(A + (size_t)(m0+srow+c*8+lrow)*K + kk + lcol, &As[(srow + c*8)*64]);
            gl_lds16(B + (size_t)(n0+srow+c*8+lrow)*K + kk + lcol, &Bs[(srow + c*8)*64]);
        }
        __syncthreads();
        #pragma unroll
        for (int ks = 0; ks < 64; ks += 32) {
            bf16x8 a[4], b[4];
            #pragma unroll
            for (int mi=0;mi<4;mi++) a[mi] = *(const bf16x8*)&As[(wm+mi*16+lr)*64 + ks + lg*8];
            #pragma unroll
            for (int ni=0;ni<4;ni++) b[ni] = *(const bf16x8*)&Bs[(wn+ni*16+lr)*64 + ks + lg*8];
            #pragma unroll
            for (int mi=0;mi<4;mi++)
                #pragma unroll
                for (int ni=0;ni<4;ni++)
                    acc[mi][ni] = __builtin_amdgcn_mfma_f32_16x16x32_bf16(a[mi], b[ni], acc[mi][ni], 0,0,0);
        }
        __syncthreads();
    }

    // repack C tile into LDS (bank-safe: stride 136)
    #pragma unroll
    for (int mi=0;mi<4;mi++)
        #pragma unroll
        for (int ni=0;ni<4;ni++)
            #pragma unroll
            for (int rr=0;rr<4;rr++)
                Cs[(wm+mi*16+lg*4+rr)*136 + wn+ni*16+lr] = f2b(acc[mi][ni][rr]);
    __syncthreads();

    const int rsub = t >> 4;            // 0..15
    const int c8   = (t & 15) * 8;      // constant per thread across store loop

    if (FUSE == 0 || n0 < 1024) {
        // plain coalesced store (stride = Nout for FUSE=0, 1024 for FUSE=1 z-tiles)
        const int strd = (FUSE == 0) ? Nout : 1024;
        #pragma unroll
        for (int it = 0; it < 8; it++) {
            int row = it*16 + rsub;
            int gcol = n0 + c8;
            if (FUSE == 0 && gcol >= Nout) continue;
            *(uint4*)(C + (size_t)(m0+row)*strd + gcol) = *(const uint4*)&Cs[row*136 + c8];
        }
    } else if (n0 < 2304) {
        // depthwise causal conv + silu -> xbcc
        const int cbase = n0 - 1024 + c8;
        float4 wreg[8]; float bias[8];
        #pragma unroll
        for (int e=0;e<8;e++) wreg[e] = *(const float4*)(cw + (size_t)(cbase+e)*4);
        {
            float4 b0 = *(const float4*)(cb + cbase);
            float4 b1 = *(const float4*)(cb + cbase + 4);
            bias[0]=b0.x; bias[1]=b0.y; bias[2]=b0.z; bias[3]=b0.w;
            bias[4]=b1.x; bias[5]=b1.y; bias[6]=b1.z; bias[7]=b1.w;
        }
        #pragma unroll
        for (int it = 0; it < 8; it++) {
            int row = it*16 + rsub;
            int sl  = row & (SEQ-1);
            float m3 = (sl >= 3) ? 1.f : 0.f;
            float m2 = (sl >= 2) ? 1.f : 0.f;
            float m1 = (sl >= 1) ? 1.f : 0.f;
            const bf16* sm3 = &Cs[(row-3)*136 + c8];
            const bf16* sm2 = &Cs[(row-2)*136 + c8];
            const bf16* sm1 = &Cs[(row-1)*136 + c8];
            const bf16* sm0 = &Cs[(row  )*136 + c8];
            float a[8];
            #pragma unroll
            for (int e=0;e<8;e++) {
                a[e] = bias[e]
                     + m3 * b2f(sm3[e]) * wreg[e].x
                     + m2 * b2f(sm2[e]) * wreg[e].y
                     + m1 * b2f(sm1[e]) * wreg[e].z
                     +      b2f(sm0[e]) * wreg[e].w;
            }
            bf16 outv[8];
            #pragma unroll
            for (int e=0;e<8;e++) outv[e] = f2b(a[e] / (1.f + __expf(-a[e])));
            *(uint4*)(xbcc + (size_t)(m0+row)*CONV_DIM + cbase) = *(uint4*)&outv[0];
        }
    } else {
        // dt tile: softplus + cumsum scan over each sequence, write dt/cum f32
        for (int p = wid; p < 32; p += 4) {       // (seq-in-tile, head)
            int sq = p >> 4, head = p & 15;
            float raw = b2f(Cs[(sq*64 + lane)*136 + head]) + dt_bias[head];
            float dval = (raw > 20.f) ? raw : log1pf(__expf(raw));
            float Ah = -__expf(A_log[head]);
            float cc = dval * Ah;
            #pragma unroll
            for (int o=1;o<64;o<<=1) { float v = __shfl_up(cc, o); if (lane >= o) cc += v; }
            int tok = m0 + sq*64 + lane;
            dt [(size_t)head*ctok + tok] = dval;
            cum[(size_t)head*ctok + tok] = cc;
        }
    }
}

// ---------------- SSD core: per (chunk-local) batch ----------------
__global__ __launch_bounds__(256) void k_ssd(const bf16* __restrict__ xbcc,
        const float* __restrict__ dt, const float* __restrict__ cum,
        const float* __restrict__ Dskip, bf16* __restrict__ y, int ctok) {
    __shared__ float scores[64][66];
    __shared__ float W[64][66];
    __shared__ __align__(16) bf16 xs[64][64];
    __shared__ float cuml[64], dtl[64];
    const int b = blockIdx.x;
    const int t = threadIdx.x;
    const size_t tokbase = (size_t)b*SEQ;
    const int lane = t & 63, lr = lane & 15, lg = lane >> 4;

    {   // scores via MFMA: wave w handles rows [w*16, w*16+16)
        int i0 = (t>>6)*16;
        f32x4 sacc[4] = {};
        const bf16* Cbase = xbcc + tokbase*CONV_DIM + D_INNER + D_STATE;
        const bf16* Bbase = xbcc + tokbase*CONV_DIM + D_INNER;
        #pragma unroll
        for (int ks = 0; ks < D_STATE; ks += 32) {
            bf16x8 af = *(const bf16x8*)(Cbase + (size_t)(i0+lr)*CONV_DIM + ks + lg*8);
            #pragma unroll
            for (int jt = 0; jt < 4; jt++) {
                bf16x8 bfr = *(const bf16x8*)(Bbase + (size_t)(jt*16+lr)*CONV_DIM + ks + lg*8);
                sacc[jt] = __builtin_amdgcn_mfma_f32_16x16x32_bf16(af, bfr, sacc[jt], 0,0,0);
            }
        }
        #pragma unroll
        for (int jt=0;jt<4;jt++)
            #pragma unroll
            for (int r=0;r<4;r++)
                scores[i0 + lg*4 + r][jt*16 + lr] = sacc[jt][r];
    }

    for (int hh = 0; hh < NHEADS; hh++) {
        __syncthreads();
        if (t < 64) {
            cuml[t] = cum[(size_t)hh*ctok + tokbase + t];
            dtl[t]  = dt [(size_t)hh*ctok + tokbase + t];
        }
        for (int ch = t; ch < 64*8; ch += 256) {
            int r = ch >> 3, c = (ch & 7)*8;
            *(uint4*)&xs[r][c] = *(const uint4*)(xbcc + (tokbase + r)*CONV_DIM + hh*HEADDIM + c);
        }
        __syncthreads();
        for (int pi = t; pi < 4096; pi += 256) {
            int i = pi >> 6, j = pi & 63;
            W[i][j] = (j <= i) ? scores[i][j] * __expf(cuml[i]-cuml[j]) * dtl[j] : 0.f;
        }
        __syncthreads();
        {
            int i = t >> 2, pg = (t & 3) * 16;
            float acc[16];
            #pragma unroll
            for (int e=0;e<16;e++) acc[e]=0.f;
            for (int j = 0; j <= i; j++) {
                float wv = W[i][j];
                const unsigned* xp = (const unsigned*)&xs[j][pg];
                #pragma unroll
                for (int e=0;e<8;e++) {
                    unsigned u = xp[e];
                    acc[2*e]   += wv * bflo(u);
                    acc[2*e+1] += wv * bfhi(u);
                }
            }
            float dsk = Dskip[hh];
            const unsigned* xi = (const unsigned*)&xs[i][pg];
            bf16 outv[16];
            #pragma unroll
            for (int e=0;e<8;e++) {
                unsigned u = xi[e];
                outv[2*e]   = f2b(acc[2*e]   + dsk*bflo(u));
                outv[2*e+1] = f2b(acc[2*e+1] + dsk*bfhi(u));
            }
            bf16* dst = y + (tokbase + i)*D_INNER + hh*HEADDIM + pg;
            *(uint4*)dst     = *(uint4*)&outv[0];
            *(uint4*)(dst+8) = *(uint4*)&outv[8];
        }
    }
}

// ---------------- y = y*silu(z); RMS-norm * norm_w (in place, bf16) ----------------
__global__ __launch_bounds__(256) void k_gaterms(bf16* __restrict__ y,
        const bf16* __restrict__ zbuf, const float* __restrict__ nw) {
    int tok = blockIdx.x, t = threadIdx.x;
    __shared__ float red[4];
    int d = t*4;
    uint2 yv = *(const uint2*)(y    + (size_t)tok*D_INNER + d);
    uint2 zv = *(const uint2*)(zbuf + (size_t)tok*D_INNER + d);
    const unsigned* yu = (const unsigned*)&yv;
    const unsigned* zu = (const unsigned*)&zv;
    float g[4]; float ss = 0.f;
    #pragma unroll
    for (int e=0;e<2;e++) {
        float y0 = bflo(yu[e]), y1 = bfhi(yu[e]);
        float z0 = bflo(zu[e]), z1 = bfhi(zu[e]);
        float g0 = y0 * z0 / (1.f + __expf(-z0));
        float g1 = y1 * z1 / (1.f + __expf(-z1));
        g[2*e] = g0; g[2*e+1] = g1;
        ss += g0*g0 + g1*g1;
    }
    for (int o=32;o>0;o>>=1) ss += __shfl_down(ss, o);
    if ((t & 63) == 0) red[t>>6] = ss;
    __syncthreads();
    float tot = red[0]+red[1]+red[2]+red[3];
    float scale = rsqrtf(tot/(float)D_INNER + EPS);
    bf16 outv[4];
    #pragma unroll
    for (int e=0;e<4;e++) outv[e] = f2b(g[e] * scale * nw[d+e]);
    *(uint2*)(y + (size_t)tok*D_INNER + d) = *(uint2*)&outv[0];
}

// ---------------- h += layernorm(tmp)*g + b; refresh hb ----------------
__global__ __launch_bounds__(256) void k_resln(float* __restrict__ h,
        bf16* __restrict__ hb, const bf16* __restrict__ tmp,
        const float* __restrict__ g, const float* __restrict__ bb) {
    int tok = blockIdx.x, t = threadIdx.x;
    __shared__ float redS[4], redQ[4];
    int d = t*2;
    unsigned u = *(const unsigned*)(tmp + (size_t)tok*D_MODEL + d);
    float v0 = bflo(u), v1 = bfhi(u);
    float s = v0+v1, q = v0*v0+v1*v1;
    for (int o=32;o>0;o>>=1){ s += __shfl_down(s,o); q += __shfl_down(q,o); }
    if ((t&63)==0){ redS[t>>6]=s; redQ[t>>6]=q; }
    __syncthreads();
    float S = redS[0]+redS[1]+redS[2]+redS[3];
    float Q = redQ[0]+redQ[1]+redQ[2]+redQ[3];
    float mu  = S/(float)D_MODEL;
    float var = Q/(float)D_MODEL - mu*mu;
    float inv = rsqrtf(var + EPS);
    size_t base = (size_t)tok*D_MODEL + d;
    float h0 = h[base]   + (v0-mu)*inv*g[d]   + bb[d];
    float h1 = h[base+1] + (v1-mu)*inv*g[d+1] + bb[d+1];
    h[base] = h0; h[base+1] = h1;
    bf16 o2[2] = { f2b(h0), f2b(h1) };
    *(unsigned*)(hb + base) = *(unsigned*)&o2[0];
}

// ---------------- masked mean-pool over s ----------------
__global__ __launch_bounds__(256) void k_pool(const float* __restrict__ h,
        float* __restrict__ pooled) {
    int b = blockIdx.x, t = threadIdx.x;
    __shared__ float ps[64][4];
    __shared__ float pm[64];
    __shared__ float cntS;
    {
        int s = t >> 2, q = t & 3;
        const float4* row = (const float4*)(h + ((size_t)b*SEQ + s)*D_MODEL + q*128);
        float acc = 0;
        #pragma unroll 8
        for (int e=0;e<32;e++) { float4 f = row[e]; acc += f.x+f.y+f.z+f.w; }
        ps[s][q] = acc;
    }
    __syncthreads();
    if (t < 64) pm[t] = (ps[t][0]+ps[t][1]+ps[t][2]+ps[t][3]) != 0.f ? 1.f : 0.f;
    __syncthreads();
    if (t == 0) { float c=0; for (int s2=0;s2<64;s2++) c+=pm[s2]; cntS = fmaxf(c,1.f); }
    __syncthreads();
    float cnt = cntS;
    #pragma unroll
    for (int rep=0;rep<2;rep++) {
        int d = t + rep*256;
        float acc = 0;
        for (int s2=0;s2<64;s2++) acc += h[((size_t)b*SEQ+s2)*D_MODEL + d] * pm[s2];
        pooled[(size_t)b*D_MODEL + d] = acc / cnt;
    }
}

// ---------------- fc1(relu) + fc2 ----------------
__global__ __launch_bounds__(128) void k_fc(const float* __restrict__ pooled,
        const float* __restrict__ w1, const float* __restrict__ b1,
        const float* __restrict__ w2, const float* __restrict__ b2,
        float* __restrict__ out) {
    int b = blockIdx.x, j = threadIdx.x;
    __shared__ float hid[FC_HID];
    const float* p  = pooled + (size_t)b*D_MODEL;
    const float* wr = w1 + (size_t)j*D_MODEL;
    float acc = b1[j];
    for (int d=0; d<D_MODEL; d+=4)
        acc += p[d]*wr[d] + p[d+1]*wr[d+1] + p[d+2]*wr[d+2] + p[d+3]*wr[d+3];
    hid[j] = fmaxf(acc, 0.f);
    __syncthreads();
    if (j < 2) {
        float o = b2[j];
        for (int k=0;k<FC_HID;k++) o += hid[k]*w2[j*FC_HID+k];
        out[b*2 + j] = o;
    }
}

extern "C" void kernel_launch(void* const* d_in, const int* in_sizes, int n_in,
                              void* d_out, int out_size, void* d_ws, size_t ws_size,
                              hipStream_t stream) {
    (void)in_sizes; (void)n_in; (void)out_size;
    const int*   x        = (const int*)  d_in[0];
    const float* emb      = (const float*)d_in[1];
    const float* pos      = (const float*)d_in[2];
    const float* in_proj  = (const float*)d_in[3];
    const float* conv_w   = (const float*)d_in[4];
    const float* conv_b   = (const float*)d_in[5];
    const float* dt_bias  = (const float*)d_in[6];
    const float* A_log    = (const float*)d_in[7];
    const float* D_skip   = (const float*)d_in[8];
    const float* norm_w   = (const float*)d_in[9];
    const float* out_proj = (const float*)d_in[10];
    const float* ln_g     = (const float*)d_in[11];
    const float* ln_b     = (const float*)d_in[12];
    const float* fc1_w    = (const float*)d_in[13];
    const float* fc1_b    = (const float*)d_in[14];
    const float* fc2_w    = (const float*)d_in[15];
    const float* fc2_b    = (const float*)d_in[16];
    float* out = (float*)d_out;

    // ---- persistent region ----
    const size_t H_B   = (size_t)NTOK * D_MODEL * 4;     // 64 MB f32 h
    const size_t HB_B  = (size_t)NTOK * D_MODEL * 2;     // 32 MB bf16 shadow
    const size_t WPI_B = (size_t)NPAD * D_MODEL * 2;     // per layer 2.49 MB
    const size_t WPO_B = (size_t)D_MODEL * D_INNER * 2;  // per layer 1 MB
    const size_t PBASE = H_B + HB_B + NLAYERS*(WPI_B + WPO_B);

    // transients per token: z 2048 + xbcc 2560 + ybuf 2048 + dt/cum 128
    const size_t PER_TOK = 2048 + 2560 + 2048 + 128;     // 6784 B
    int CB = BATCH;
    while (CB > 8 && PBASE + (size_t)CB*SEQ*PER_TOK > ws_size) CB >>= 1;
    const int CT = CB * SEQ;
    const int NC = BATCH / CB;

    char* ws = (char*)d_ws;
    float* h    = (float*)(ws);
    bf16*  hb   = (bf16*) (ws + H_B);
    bf16*  wpi  = (bf16*) (ws + H_B + HB_B);                   // [NLAYERS][NPAD][512]
    bf16*  wpo  = (bf16*) (ws + H_B + HB_B + NLAYERS*WPI_B);   // [NLAYERS][512][1024]
    char*  tr   = ws + PBASE;
    bf16*  zbuf = (bf16*) (tr);                                // CT*1024
    bf16*  xbcc = (bf16*) (tr + (size_t)CT*2048);              // CT*1280
    bf16*  ybuf = (bf16*) (tr + (size_t)CT*(2048+2560));       // CT*1024
    float* dt   = (float*)(tr + (size_t)CT*(2048+2560+2048));  // [16][CT]
    float* cum  = dt + (size_t)CT*NHEADS;
    bf16*  tmp  = xbcc;                 // alias: xbcc dead after k_ssd
    float* pooled = (float*)tr;

    // weight conversion (both layers, once per launch)
    for (int l = 0; l < NLAYERS; l++) {
        int t8i = NPAD*D_MODEL/8;
        k_cvtw<<<(t8i+255)/256, 256, 0, stream>>>(in_proj + (size_t)l*D_IN_PROJ*D_MODEL,
                wpi + (size_t)l*NPAD*D_MODEL, D_IN_PROJ, D_MODEL, t8i);
        int t8o = D_MODEL*D_INNER/8;
        k_cvtw<<<(t8o+255)/256, 256, 0, stream>>>(out_proj + (size_t)l*D_MODEL*D_INNER,
                wpo + (size_t)l*D_MODEL*D_INNER, D_MODEL, D_INNER, t8o);
    }

    k_embed<<<(NTOK*D_MODEL)/256, 256, 0, stream>>>(x, emb, pos, h, hb);

    const int NBX_I = NPAD/128;     // 19
    const int NBX_O = D_MODEL/128;  // 4

    for (int l = 0; l < NLAYERS; l++) {
        const bf16* wi = wpi + (size_t)l*NPAD*D_MODEL;
        const bf16* wo = wpo + (size_t)l*D_MODEL*D_INNER;
        for (int c = 0; c < NC; c++) {
            const int tok0 = c * CT;
            float* hc  = h  + (size_t)tok0 * D_MODEL;
            bf16*  hbc = hb + (size_t)tok0 * D_MODEL;
            k_gemm128<1><<<(CT/128)*NBX_I, 256, 0, stream>>>(hbc, wi, zbuf,
                    xbcc, dt, cum,
                    conv_w + (size_t)l*CONV_DIM*D_CONV, conv_b + (size_t)l*CONV_DIM,
                    dt_bias + l*NHEADS, A_log + l*NHEADS,
                    NPAD, D_MODEL, NBX_I, CT);
            k_ssd<<<CB, 256, 0, stream>>>(xbcc, dt, cum, D_skip + l*NHEADS, ybuf, CT);
            k_gaterms<<<CT, 256, 0, stream>>>(ybuf, zbuf, norm_w + (size_t)l*D_INNER);
            k_gemm128<0><<<(CT/128)*NBX_O, 256, 0, stream>>>(ybuf, wo, tmp,
                    nullptr, nullptr, nullptr, nullptr, nullptr, nullptr, nullptr,
                    D_MODEL, D_INNER, NBX_O, CT);
            k_resln<<<CT, 256, 0, stream>>>(hc, hbc, tmp, ln_g + l*D_MODEL, ln_b + l*D_MODEL);
        }
    }

    k_pool<<<BATCH, 256, 0, stream>>>(h, pooled);
    k_fc<<<BATCH, FC_HID, 0, stream>>>(pooled, fc1_w, fc1_b, fc2_w, fc2_b, out);
}

// Round 6
// 806.457 us; speedup vs baseline: 2.6800x; 1.4762x over previous
//
#include <hip/hip_runtime.h>
#include <hip/hip_bf16.h>

// ---- problem constants ----
#define D_MODEL   512
#define D_STATE   128
#define D_CONV    4
#define HEADDIM   64
#define NLAYERS   2
#define D_INNER   1024
#define NHEADS    16
#define CONV_DIM  1280          // D_INNER + 2*D_STATE
#define D_IN_PROJ 2320          // 2*D_INNER + 2*D_STATE + NHEADS
#define NPAD      2432          // D_IN_PROJ padded to 128
#define SEQ       64
#define BATCH     512
#define NTOK      (BATCH*SEQ)   // 32768
#define FC_HID    128
#define EPS       1e-5f

using bf16 = __hip_bfloat16;
typedef __bf16 bf16x8 __attribute__((ext_vector_type(8)));
typedef float  f32x4  __attribute__((ext_vector_type(4)));

__device__ __forceinline__ float b2f(bf16 v)  { return __bfloat162float(v); }
__device__ __forceinline__ bf16  f2b(float v) { return __float2bfloat16(v); }
__device__ __forceinline__ float bflo(unsigned u){ return __builtin_bit_cast(float, u << 16); }
__device__ __forceinline__ float bfhi(unsigned u){ return __builtin_bit_cast(float, u & 0xffff0000u); }

__device__ __forceinline__ void gl_lds16(const void* g, void* l) {
    __builtin_amdgcn_global_load_lds((const __attribute__((address_space(1))) void*)g,
                                     (__attribute__((address_space(3))) void*)l, 16, 0, 0);
}

// ---------------- embedding: h = emb[x]+pos (f32) and bf16 shadow hb ----------------
__global__ __launch_bounds__(256) void k_embed(const int* __restrict__ x,
        const float* __restrict__ emb, const float* __restrict__ pos,
        float* __restrict__ h, bf16* __restrict__ hb) {
    int idx = blockIdx.x*256 + threadIdx.x;     // NTOK*D_MODEL
    int d   = idx & (D_MODEL-1);
    int tok = idx >> 9;
    int s   = tok & (SEQ-1);
    int v   = x[tok];
    float r = emb[v*D_MODEL + d] + pos[s*D_MODEL + d];
    h[idx]  = r;
    hb[idx] = f2b(r);
}

// ---------------- weight convert f32 -> bf16, zero-padded rows ----------------
__global__ __launch_bounds__(256) void k_cvtw(const float* __restrict__ src,
        bf16* __restrict__ dst, int R, int Kc, int total8) {
    int idx = blockIdx.x*256 + threadIdx.x;
    if (idx >= total8) return;
    int e0 = idx*8;
    int r = e0 / Kc, c = e0 % Kc;
    bf16 tb[8];
    if (r < R) {
        float4 f0 = *(const float4*)(src + (size_t)r*Kc + c);
        float4 f1 = *(const float4*)(src + (size_t)r*Kc + c + 4);
        tb[0]=f2b(f0.x); tb[1]=f2b(f0.y); tb[2]=f2b(f0.z); tb[3]=f2b(f0.w);
        tb[4]=f2b(f1.x); tb[5]=f2b(f1.y); tb[6]=f2b(f1.z); tb[7]=f2b(f1.w);
    } else {
        #pragma unroll
        for (int e=0;e<8;e++) tb[e] = f2b(0.f);
    }
    *(uint4*)(dst + (size_t)r*Kc + c) = *(uint4*)&tb[0];
}

// ---------------- GEMM 128x128: C = A[M,K] * B[Npad,K]^T (bf16 in, bf16 out) ----------------
// FUSE=0: plain store to C[M][Nout].
// FUSE=1: in_proj epilogue — n0<1024: raw z -> C (zbuf, stride 1024);
//         1024<=n0<2304: depthwise causal conv(k=4)+silu -> xbcc (stride 1280);
//         n0==2304: softplus+cumsum scan -> dt, cum ([head][ctok] f32).
template<int FUSE>
__global__ __launch_bounds__(256) void k_gemm128(const bf16* __restrict__ A,
        const bf16* __restrict__ B, bf16* __restrict__ C,
        bf16* __restrict__ xbcc, float* __restrict__ dt, float* __restrict__ cum,
        const float* __restrict__ cw, const float* __restrict__ cb,
        const float* __restrict__ dt_bias, const float* __restrict__ A_log,
        int Nout, int K, int nbx, int ctok)
{
    __shared__ __align__(16) char ldsbuf[128*136*2];   // 34816 B
    bf16* As = (bf16*)ldsbuf;                          // [128][64]
    bf16* Bs = (bf16*)(ldsbuf + 16384);                // [128][64]
    bf16* Cs = (bf16*)ldsbuf;                          // [128][136] (repack)

    // bijective XCD swizzle (m204)
    const int nwg = gridDim.x;
    const int q = nwg >> 3, r = nwg & 7;
    const int xcd = blockIdx.x & 7, loc = blockIdx.x >> 3;
    const int wg = ((xcd < r) ? xcd*(q+1) : r*(q+1) + (xcd-r)*q) + loc;
    const int m0 = (wg / nbx) * 128;
    const int n0 = (wg % nbx) * 128;

    const int t = threadIdx.x;
    const int wid = t >> 6, lane = t & 63;
    const int lr = lane & 15, lg = lane >> 4;
    const int wm = (wid >> 1)*64, wn = (wid & 1)*64;
    const int srow = wid*32, lrow = lane >> 3, lcol = (lane & 7)*8;

    f32x4 acc[4][4] = {};

    for (int kk = 0; kk < K; kk += 64) {
        #pragma unroll
        for (int c = 0; c < 4; c++) {
            gl_lds16(A + (size_t)(m0+srow+c*8+lrow)*K + kk + lcol, &As[(srow + c*8)*64]);
            gl_lds16(B + (size_t)(n0+srow+c*8+lrow)*K + kk + lcol, &Bs[(srow + c*8)*64]);
        }
        __syncthreads();
        #pragma unroll
        for (int ks = 0; ks < 64; ks += 32) {
            bf16x8 a[4], b[4];
            #pragma unroll
            for (int mi=0;mi<4;mi++) a[mi] = *(const bf16x8*)&As[(wm+mi*16+lr)*64 + ks + lg*8];
            #pragma unroll
            for (int ni=0;ni<4;ni++) b[ni] = *(const bf16x8*)&Bs[(wn+ni*16+lr)*64 + ks + lg*8];
            #pragma unroll
            for (int mi=0;mi<4;mi++)
                #pragma unroll
                for (int ni=0;ni<4;ni++)
                    acc[mi][ni] = __builtin_amdgcn_mfma_f32_16x16x32_bf16(a[mi], b[ni], acc[mi][ni], 0,0,0);
        }
        __syncthreads();
    }

    // repack C tile into LDS (bank-safe: stride 136)
    #pragma unroll
    for (int mi=0;mi<4;mi++)
        #pragma unroll
        for (int ni=0;ni<4;ni++)
            #pragma unroll
            for (int rr=0;rr<4;rr++)
                Cs[(wm+mi*16+lg*4+rr)*136 + wn+ni*16+lr] = f2b(acc[mi][ni][rr]);
    __syncthreads();

    const int rsub = t >> 4;            // 0..15
    const int c8   = (t & 15) * 8;      // constant per thread across store loop

    if (FUSE == 0 || n0 < 1024) {
        // plain coalesced store (stride = Nout for FUSE=0, 1024 for FUSE=1 z-tiles)
        const int strd = (FUSE == 0) ? Nout : 1024;
        #pragma unroll
        for (int it = 0; it < 8; it++) {
            int row = it*16 + rsub;
            int gcol = n0 + c8;
            if (FUSE == 0 && gcol >= Nout) continue;
            *(uint4*)(C + (size_t)(m0+row)*strd + gcol) = *(const uint4*)&Cs[row*136 + c8];
        }
    } else if (n0 < 2304) {
        // depthwise causal conv + silu -> xbcc
        const int cbase = n0 - 1024 + c8;
        float4 wreg[8]; float bias[8];
        #pragma unroll
        for (int e=0;e<8;e++) wreg[e] = *(const float4*)(cw + (size_t)(cbase+e)*4);
        {
            float4 b0 = *(const float4*)(cb + cbase);
            float4 b1 = *(const float4*)(cb + cbase + 4);
            bias[0]=b0.x; bias[1]=b0.y; bias[2]=b0.z; bias[3]=b0.w;
            bias[4]=b1.x; bias[5]=b1.y; bias[6]=b1.z; bias[7]=b1.w;
        }
        #pragma unroll
        for (int it = 0; it < 8; it++) {
            int row = it*16 + rsub;
            int sl  = row & (SEQ-1);
            float m3 = (sl >= 3) ? 1.f : 0.f;
            float m2 = (sl >= 2) ? 1.f : 0.f;
            float m1 = (sl >= 1) ? 1.f : 0.f;
            const bf16* sm3 = &Cs[(row-3)*136 + c8];
            const bf16* sm2 = &Cs[(row-2)*136 + c8];
            const bf16* sm1 = &Cs[(row-1)*136 + c8];
            const bf16* sm0 = &Cs[(row  )*136 + c8];
            float a[8];
            #pragma unroll
            for (int e=0;e<8;e++) {
                a[e] = bias[e]
                     + m3 * b2f(sm3[e]) * wreg[e].x
                     + m2 * b2f(sm2[e]) * wreg[e].y
                     + m1 * b2f(sm1[e]) * wreg[e].z
                     +      b2f(sm0[e]) * wreg[e].w;
            }
            bf16 outv[8];
            #pragma unroll
            for (int e=0;e<8;e++) outv[e] = f2b(a[e] / (1.f + __expf(-a[e])));
            *(uint4*)(xbcc + (size_t)(m0+row)*CONV_DIM + cbase) = *(uint4*)&outv[0];
        }
    } else {
        // dt tile: softplus + cumsum scan over each sequence, write dt/cum f32
        for (int p = wid; p < 32; p += 4) {       // (seq-in-tile, head)
            int sq = p >> 4, head = p & 15;
            float raw = b2f(Cs[(sq*64 + lane)*136 + head]) + dt_bias[head];
            float dval = (raw > 20.f) ? raw : log1pf(__expf(raw));
            float Ah = -__expf(A_log[head]);
            float cc = dval * Ah;
            #pragma unroll
            for (int o=1;o<64;o<<=1) { float v = __shfl_up(cc, o); if (lane >= o) cc += v; }
            int tok = m0 + sq*64 + lane;
            dt [(size_t)head*ctok + tok] = dval;
            cum[(size_t)head*ctok + tok] = cc;
        }
    }
}

// ---------------- SSD core v2: MFMA for y = W @ xs ----------------
// Grid = CB*2 blocks: block handles batch b = bid>>1, heads hg..hg+7 (hg = (bid&1)*8).
// scores = Cm·Bm^T via MFMA (per block). Per head:
//   Wb[i][j] = (j<=i) ? scores[i][j]*exp(cum[i]-cum[j])*dt[j] : 0   (bf16, LDS)
//   xsT[p][j] = xs[j][p]                                            (bf16, LDS)
//   y[i][p]  = sum_j Wb[i][j]*xsT[p][j]  (MFMA)  + Dskip*xsT[p][i]
__global__ __launch_bounds__(256) void k_ssd(const bf16* __restrict__ xbcc,
        const float* __restrict__ dt, const float* __restrict__ cum,
        const float* __restrict__ Dskip, bf16* __restrict__ y, int ctok) {
    __shared__ float scores[64][66];                       // 16896 B
    __shared__ __align__(16) bf16 Wb [64][72];             // 9216 B (rows 144B = 16B-aligned)
    __shared__ __align__(16) bf16 xsT[64][72];             // 9216 B
    __shared__ __align__(16) bf16 ys [64][72];             // 9216 B
    const int bid = blockIdx.x;
    const int b   = bid >> 1;
    const int hg  = (bid & 1) * 8;
    const int t = threadIdx.x;
    const size_t tokbase = (size_t)b*SEQ;
    const int lane = t & 63, lr = lane & 15, lg = lane >> 4;
    const int w = t >> 6;

    {   // scores via MFMA: wave w handles rows [w*16, w*16+16)
        int i0 = w*16;
        f32x4 sacc[4] = {};
        const bf16* Cbase = xbcc + tokbase*CONV_DIM + D_INNER + D_STATE;
        const bf16* Bbase = xbcc + tokbase*CONV_DIM + D_INNER;
        #pragma unroll
        for (int ks = 0; ks < D_STATE; ks += 32) {
            bf16x8 af = *(const bf16x8*)(Cbase + (size_t)(i0+lr)*CONV_DIM + ks + lg*8);
            #pragma unroll
            for (int jt = 0; jt < 4; jt++) {
                bf16x8 bfr = *(const bf16x8*)(Bbase + (size_t)(jt*16+lr)*CONV_DIM + ks + lg*8);
                sacc[jt] = __builtin_amdgcn_mfma_f32_16x16x32_bf16(af, bfr, sacc[jt], 0,0,0);
            }
        }
        #pragma unroll
        for (int jt=0;jt<4;jt++)
            #pragma unroll
            for (int rr=0;rr<4;rr++)
                scores[i0 + lg*4 + rr][jt*16 + lr] = sacc[jt][rr];
    }

    // Wb-build indices (per thread): row i, col group j0..j0+15
    const int wi = t >> 2;
    const int wj0 = (t & 3) * 16;

    for (int hl = 0; hl < 8; hl++) {
        const int hh = hg + hl;
        const size_t cbase = (size_t)hh*ctok + tokbase;
        __syncthreads();   // prev MFMA/store readers done; scores ready on first iter

        // ---- phase 1: stage xsT (transpose) + build Wb ----
        #pragma unroll
        for (int cc = 0; cc < 2; cc++) {
            int ch = cc*256 + t;
            int rr = ch >> 3, c8 = (ch & 7)*8;
            uint4 v = *(const uint4*)(xbcc + (tokbase + rr)*CONV_DIM + hh*HEADDIM + c8);
            const bf16* pv = (const bf16*)&v;
            #pragma unroll
            for (int e=0;e<8;e++) xsT[c8+e][rr] = pv[e];
        }
        {
            float cum_i = cum[cbase + wi];
            float cjf[16], djf[16];
            #pragma unroll
            for (int qq=0; qq<4; qq++) {
                float4 a4 = *(const float4*)(cum + cbase + wj0 + qq*4);
                float4 d4 = *(const float4*)(dt  + cbase + wj0 + qq*4);
                cjf[qq*4+0]=a4.x; cjf[qq*4+1]=a4.y; cjf[qq*4+2]=a4.z; cjf[qq*4+3]=a4.w;
                djf[qq*4+0]=d4.x; djf[qq*4+1]=d4.y; djf[qq*4+2]=d4.z; djf[qq*4+3]=d4.w;
            }
            bf16 tb[16];
            #pragma unroll
            for (int e=0;e<16;e++) {
                int j = wj0 + e;
                float wv = (j <= wi) ? scores[wi][j] * __expf(cum_i - cjf[e]) * djf[e] : 0.f;
                tb[e] = f2b(wv);
            }
            *(uint4*)&Wb[wi][wj0]   = *(uint4*)&tb[0];
            *(uint4*)&Wb[wi][wj0+8] = *(uint4*)&tb[8];
        }
        __syncthreads();

        // ---- phase 2: MFMA y = Wb @ xsT^T, + D_skip*xs, write ys ----
        {
            float dsk = Dskip[hh];
            f32x4 yacc[4] = {};
            #pragma unroll
            for (int ks = 0; ks < 64; ks += 32) {
                bf16x8 a = *(const bf16x8*)&Wb[w*16 + lr][ks + lg*8];
                #pragma unroll
                for (int n=0; n<4; n++) {
                    bf16x8 bb = *(const bf16x8*)&xsT[n*16 + lr][ks + lg*8];
                    yacc[n] = __builtin_amdgcn_mfma_f32_16x16x32_bf16(a, bb, yacc[n], 0,0,0);
                }
            }
            #pragma unroll
            for (int n=0; n<4; n++)
                #pragma unroll
                for (int rr=0; rr<4; rr++) {
                    int row = w*16 + lg*4 + rr;
                    int col = n*16 + lr;
                    ys[row][col] = f2b(yacc[n][rr] + dsk * b2f(xsT[col][row]));
                }
        }
        __syncthreads();

        // ---- phase 3: coalesced store ys -> ybuf ----
        #pragma unroll
        for (int cc = 0; cc < 2; cc++) {
            int ch = cc*256 + t;
            int rr = ch >> 3, c8 = (ch & 7)*8;
            *(uint4*)(y + (tokbase + rr)*D_INNER + hh*HEADDIM + c8) = *(const uint4*)&ys[rr][c8];
        }
    }
}

// ---------------- y = y*silu(z); RMS-norm * norm_w (in place, bf16) ----------------
__global__ __launch_bounds__(256) void k_gaterms(bf16* __restrict__ y,
        const bf16* __restrict__ zbuf, const float* __restrict__ nw) {
    int tok = blockIdx.x, t = threadIdx.x;
    __shared__ float red[4];
    int d = t*4;
    uint2 yv = *(const uint2*)(y    + (size_t)tok*D_INNER + d);
    uint2 zv = *(const uint2*)(zbuf + (size_t)tok*D_INNER + d);
    const unsigned* yu = (const unsigned*)&yv;
    const unsigned* zu = (const unsigned*)&zv;
    float g[4]; float ss = 0.f;
    #pragma unroll
    for (int e=0;e<2;e++) {
        float y0 = bflo(yu[e]), y1 = bfhi(yu[e]);
        float z0 = bflo(zu[e]), z1 = bfhi(zu[e]);
        float g0 = y0 * z0 / (1.f + __expf(-z0));
        float g1 = y1 * z1 / (1.f + __expf(-z1));
        g[2*e] = g0; g[2*e+1] = g1;
        ss += g0*g0 + g1*g1;
    }
    for (int o=32;o>0;o>>=1) ss += __shfl_down(ss, o);
    if ((t & 63) == 0) red[t>>6] = ss;
    __syncthreads();
    float tot = red[0]+red[1]+red[2]+red[3];
    float scale = rsqrtf(tot/(float)D_INNER + EPS);
    bf16 outv[4];
    #pragma unroll
    for (int e=0;e<4;e++) outv[e] = f2b(g[e] * scale * nw[d+e]);
    *(uint2*)(y + (size_t)tok*D_INNER + d) = *(uint2*)&outv[0];
}

// ---------------- h += layernorm(tmp)*g + b; refresh hb ----------------
__global__ __launch_bounds__(256) void k_resln(float* __restrict__ h,
        bf16* __restrict__ hb, const bf16* __restrict__ tmp,
        const float* __restrict__ g, const float* __restrict__ bb) {
    int tok = blockIdx.x, t = threadIdx.x;
    __shared__ float redS[4], redQ[4];
    int d = t*2;
    unsigned u = *(const unsigned*)(tmp + (size_t)tok*D_MODEL + d);
    float v0 = bflo(u), v1 = bfhi(u);
    float s = v0+v1, q = v0*v0+v1*v1;
    for (int o=32;o>0;o>>=1){ s += __shfl_down(s,o); q += __shfl_down(q,o); }
    if ((t&63)==0){ redS[t>>6]=s; redQ[t>>6]=q; }
    __syncthreads();
    float S = redS[0]+redS[1]+redS[2]+redS[3];
    float Q = redQ[0]+redQ[1]+redQ[2]+redQ[3];
    float mu  = S/(float)D_MODEL;
    float var = Q/(float)D_MODEL - mu*mu;
    float inv = rsqrtf(var + EPS);
    size_t base = (size_t)tok*D_MODEL + d;
    float h0 = h[base]   + (v0-mu)*inv*g[d]   + bb[d];
    float h1 = h[base+1] + (v1-mu)*inv*g[d+1] + bb[d+1];
    h[base] = h0; h[base+1] = h1;
    bf16 o2[2] = { f2b(h0), f2b(h1) };
    *(unsigned*)(hb + base) = *(unsigned*)&o2[0];
}

// ---------------- masked mean-pool over s ----------------
__global__ __launch_bounds__(256) void k_pool(const float* __restrict__ h,
        float* __restrict__ pooled) {
    int b = blockIdx.x, t = threadIdx.x;
    __shared__ float ps[64][4];
    __shared__ float pm[64];
    __shared__ float cntS;
    {
        int s = t >> 2, q = t & 3;
        const float4* row = (const float4*)(h + ((size_t)b*SEQ + s)*D_MODEL + q*128);
        float acc = 0;
        #pragma unroll 8
        for (int e=0;e<32;e++) { float4 f = row[e]; acc += f.x+f.y+f.z+f.w; }
        ps[s][q] = acc;
    }
    __syncthreads();
    if (t < 64) pm[t] = (ps[t][0]+ps[t][1]+ps[t][2]+ps[t][3]) != 0.f ? 1.f : 0.f;
    __syncthreads();
    if (t == 0) { float c=0; for (int s2=0;s2<64;s2++) c+=pm[s2]; cntS = fmaxf(c,1.f); }
    __syncthreads();
    float cnt = cntS;
    #pragma unroll
    for (int rep=0;rep<2;rep++) {
        int d = t + rep*256;
        float acc = 0;
        for (int s2=0;s2<64;s2++) acc += h[((size_t)b*SEQ+s2)*D_MODEL + d] * pm[s2];
        pooled[(size_t)b*D_MODEL + d] = acc / cnt;
    }
}

// ---------------- fc1(relu) + fc2 ----------------
__global__ __launch_bounds__(128) void k_fc(const float* __restrict__ pooled,
        const float* __restrict__ w1, const float* __restrict__ b1,
        const float* __restrict__ w2, const float* __restrict__ b2,
        float* __restrict__ out) {
    int b = blockIdx.x, j = threadIdx.x;
    __shared__ float hid[FC_HID];
    const float* p  = pooled + (size_t)b*D_MODEL;
    const float* wr = w1 + (size_t)j*D_MODEL;
    float acc = b1[j];
    for (int d=0; d<D_MODEL; d+=4)
        acc += p[d]*wr[d] + p[d+1]*wr[d+1] + p[d+2]*wr[d+2] + p[d+3]*wr[d+3];
    hid[j] = fmaxf(acc, 0.f);
    __syncthreads();
    if (j < 2) {
        float o = b2[j];
        for (int k=0;k<FC_HID;k++) o += hid[k]*w2[j*FC_HID+k];
        out[b*2 + j] = o;
    }
}

extern "C" void kernel_launch(void* const* d_in, const int* in_sizes, int n_in,
                              void* d_out, int out_size, void* d_ws, size_t ws_size,
                              hipStream_t stream) {
    (void)in_sizes; (void)n_in; (void)out_size;
    const int*   x        = (const int*)  d_in[0];
    const float* emb      = (const float*)d_in[1];
    const float* pos      = (const float*)d_in[2];
    const float* in_proj  = (const float*)d_in[3];
    const float* conv_w   = (const float*)d_in[4];
    const float* conv_b   = (const float*)d_in[5];
    const float* dt_bias  = (const float*)d_in[6];
    const float* A_log    = (const float*)d_in[7];
    const float* D_skip   = (const float*)d_in[8];
    const float* norm_w   = (const float*)d_in[9];
    const float* out_proj = (const float*)d_in[10];
    const float* ln_g     = (const float*)d_in[11];
    const float* ln_b     = (const float*)d_in[12];
    const float* fc1_w    = (const float*)d_in[13];
    const float* fc1_b    = (const float*)d_in[14];
    const float* fc2_w    = (const float*)d_in[15];
    const float* fc2_b    = (const float*)d_in[16];
    float* out = (float*)d_out;

    // ---- persistent region ----
    const size_t H_B   = (size_t)NTOK * D_MODEL * 4;     // 64 MB f32 h
    const size_t HB_B  = (size_t)NTOK * D_MODEL * 2;     // 32 MB bf16 shadow
    const size_t WPI_B = (size_t)NPAD * D_MODEL * 2;     // per layer 2.49 MB
    const size_t WPO_B = (size_t)D_MODEL * D_INNER * 2;  // per layer 1 MB
    const size_t PBASE = H_B + HB_B + NLAYERS*(WPI_B + WPO_B);

    // transients per token: z 2048 + xbcc 2560 + ybuf 2048 + dt/cum 128
    const size_t PER_TOK = 2048 + 2560 + 2048 + 128;     // 6784 B
    int CB = BATCH;
    while (CB > 8 && PBASE + (size_t)CB*SEQ*PER_TOK > ws_size) CB >>= 1;
    const int CT = CB * SEQ;
    const int NC = BATCH / CB;

    char* ws = (char*)d_ws;
    float* h    = (float*)(ws);
    bf16*  hb   = (bf16*) (ws + H_B);
    bf16*  wpi  = (bf16*) (ws + H_B + HB_B);                   // [NLAYERS][NPAD][512]
    bf16*  wpo  = (bf16*) (ws + H_B + HB_B + NLAYERS*WPI_B);   // [NLAYERS][512][1024]
    char*  tr   = ws + PBASE;
    bf16*  zbuf = (bf16*) (tr);                                // CT*1024
    bf16*  xbcc = (bf16*) (tr + (size_t)CT*2048);              // CT*1280
    bf16*  ybuf = (bf16*) (tr + (size_t)CT*(2048+2560));       // CT*1024
    float* dt   = (float*)(tr + (size_t)CT*(2048+2560+2048));  // [16][CT]
    float* cum  = dt + (size_t)CT*NHEADS;
    bf16*  tmp  = xbcc;                 // alias: xbcc dead after k_ssd
    float* pooled = (float*)tr;

    // weight conversion (both layers, once per launch)
    for (int l = 0; l < NLAYERS; l++) {
        int t8i = NPAD*D_MODEL/8;
        k_cvtw<<<(t8i+255)/256, 256, 0, stream>>>(in_proj + (size_t)l*D_IN_PROJ*D_MODEL,
                wpi + (size_t)l*NPAD*D_MODEL, D_IN_PROJ, D_MODEL, t8i);
        int t8o = D_MODEL*D_INNER/8;
        k_cvtw<<<(t8o+255)/256, 256, 0, stream>>>(out_proj + (size_t)l*D_MODEL*D_INNER,
                wpo + (size_t)l*D_MODEL*D_INNER, D_MODEL, D_INNER, t8o);
    }

    k_embed<<<(NTOK*D_MODEL)/256, 256, 0, stream>>>(x, emb, pos, h, hb);

    const int NBX_I = NPAD/128;     // 19
    const int NBX_O = D_MODEL/128;  // 4

    for (int l = 0; l < NLAYERS; l++) {
        const bf16* wi = wpi + (size_t)l*NPAD*D_MODEL;
        const bf16* wo = wpo + (size_t)l*D_MODEL*D_INNER;
        for (int c = 0; c < NC; c++) {
            const int tok0 = c * CT;
            float* hc  = h  + (size_t)tok0 * D_MODEL;
            bf16*  hbc = hb + (size_t)tok0 * D_MODEL;
            k_gemm128<1><<<(CT/128)*NBX_I, 256, 0, stream>>>(hbc, wi, zbuf,
                    xbcc, dt, cum,
                    conv_w + (size_t)l*CONV_DIM*D_CONV, conv_b + (size_t)l*CONV_DIM,
                    dt_bias + l*NHEADS, A_log + l*NHEADS,
                    NPAD, D_MODEL, NBX_I, CT);
            k_ssd<<<CB*2, 256, 0, stream>>>(xbcc, dt, cum, D_skip + l*NHEADS, ybuf, CT);
            k_gaterms<<<CT, 256, 0, stream>>>(ybuf, zbuf, norm_w + (size_t)l*D_INNER);
            k_gemm128<0><<<(CT/128)*NBX_O, 256, 0, stream>>>(ybuf, wo, tmp,
                    nullptr, nullptr, nullptr, nullptr, nullptr, nullptr, nullptr,
                    D_MODEL, D_INNER, NBX_O, CT);
            k_resln<<<CT, 256, 0, stream>>>(hc, hbc, tmp, ln_g + l*D_MODEL, ln_b + l*D_MODEL);
        }
    }

    k_pool<<<BATCH, 256, 0, stream>>>(h, pooled);
    k_fc<<<BATCH, FC_HID, 0, stream>>>(pooled, fc1_w, fc1_b, fc2_w, fc2_b, out);
}

// Round 7
// 667.204 us; speedup vs baseline: 3.2394x; 1.2087x over previous
//
#include <hip/hip_runtime.h>
#include <hip/hip_bf16.h>

// ---- problem constants ----
#define D_MODEL   512
#define D_STATE   128
#define D_CONV    4
#define HEADDIM   64
#define NLAYERS   2
#define D_INNER   1024
#define NHEADS    16
#define CONV_DIM  1280          // D_INNER + 2*D_STATE
#define D_IN_PROJ 2320          // 2*D_INNER + 2*D_STATE + NHEADS
#define NPAD      2432          // D_IN_PROJ padded to 128
#define SEQ       64
#define BATCH     512
#define NTOK      (BATCH*SEQ)   // 32768
#define FC_HID    128
#define EPS       1e-5f

using bf16 = __hip_bfloat16;
typedef __bf16 bf16x8 __attribute__((ext_vector_type(8)));
typedef float  f32x4  __attribute__((ext_vector_type(4)));

__device__ __forceinline__ float b2f(bf16 v)  { return __bfloat162float(v); }
__device__ __forceinline__ bf16  f2b(float v) { return __float2bfloat16(v); }
__device__ __forceinline__ float bflo(unsigned u){ return __builtin_bit_cast(float, u << 16); }
__device__ __forceinline__ float bfhi(unsigned u){ return __builtin_bit_cast(float, u & 0xffff0000u); }

__device__ __forceinline__ void gl_lds16(const void* g, void* l) {
    __builtin_amdgcn_global_load_lds((const __attribute__((address_space(1))) void*)g,
                                     (__attribute__((address_space(3))) void*)l, 16, 0, 0);
}

// ---------------- embedding: h = emb[x]+pos (f32) and bf16 shadow hb ----------------
__global__ __launch_bounds__(256) void k_embed(const int* __restrict__ x,
        const float* __restrict__ emb, const float* __restrict__ pos,
        float* __restrict__ h, bf16* __restrict__ hb) {
    int idx = blockIdx.x*256 + threadIdx.x;     // NTOK*D_MODEL
    int d   = idx & (D_MODEL-1);
    int tok = idx >> 9;
    int s   = tok & (SEQ-1);
    int v   = x[tok];
    float r = emb[v*D_MODEL + d] + pos[s*D_MODEL + d];
    h[idx]  = r;
    hb[idx] = f2b(r);
}

// ---------------- weight convert f32 -> bf16, zero-padded rows ----------------
__global__ __launch_bounds__(256) void k_cvtw(const float* __restrict__ src,
        bf16* __restrict__ dst, int R, int Kc, int total8) {
    int idx = blockIdx.x*256 + threadIdx.x;
    if (idx >= total8) return;
    int e0 = idx*8;
    int r = e0 / Kc, c = e0 % Kc;
    bf16 tb[8];
    if (r < R) {
        float4 f0 = *(const float4*)(src + (size_t)r*Kc + c);
        float4 f1 = *(const float4*)(src + (size_t)r*Kc + c + 4);
        tb[0]=f2b(f0.x); tb[1]=f2b(f0.y); tb[2]=f2b(f0.z); tb[3]=f2b(f0.w);
        tb[4]=f2b(f1.x); tb[5]=f2b(f1.y); tb[6]=f2b(f1.z); tb[7]=f2b(f1.w);
    } else {
        #pragma unroll
        for (int e=0;e<8;e++) tb[e] = f2b(0.f);
    }
    *(uint4*)(dst + (size_t)r*Kc + c) = *(uint4*)&tb[0];
}

// ---------------- GEMM 128x128, double-buffered counted-vmcnt pipeline ----------------
// C = A[M,KDIM] * B[Npad,KDIM]^T (bf16 in/out). LDS swizzled (slot ^= row&7) via
// pre-swizzled global source (rule #21: both-sides-or-neither).
// FUSE=0: plain store. FUSE=1: in_proj epilogue (z / conv+silu / dt-scan).
template<int FUSE, int KDIM>
__global__ __launch_bounds__(256) void k_gemm128(const bf16* __restrict__ A,
        const bf16* __restrict__ B, bf16* __restrict__ C,
        bf16* __restrict__ xbcc, float* __restrict__ dt, float* __restrict__ cum,
        const float* __restrict__ cw, const float* __restrict__ cb,
        const float* __restrict__ dt_bias, const float* __restrict__ A_log,
        int Nout, int nbx, int ctok)
{
    constexpr int NT = KDIM / 64;
    __shared__ __align__(16) char lds[65536];      // 2 buffers x (A 16K + B 16K)
    bf16* Cs = (bf16*)lds;                         // epilogue repack alias [128][136]

    // bijective XCD swizzle (m204)
    const int nwg = gridDim.x;
    const int q = nwg >> 3, r = nwg & 7;
    const int xcd = blockIdx.x & 7, loc = blockIdx.x >> 3;
    const int wg = ((xcd < r) ? xcd*(q+1) : r*(q+1) + (xcd-r)*q) + loc;
    const int m0 = (wg / nbx) * 128;
    const int n0 = (wg % nbx) * 128;

    const int t = threadIdx.x;
    const int wid = t >> 6, lane = t & 63;
    const int lr = lane & 15, lg = lane >> 4;
    const int wm = (wid >> 1)*64, wn = (wid & 1)*64;
    const int srow = wid*32;
    const int sr   = lane >> 3;                    // row-in-chunk 0..7
    const int scol = ((lane & 7) ^ sr) * 8;        // pre-swizzled source slot

    const bf16* Abase = A + (size_t)(m0 + srow + sr)*KDIM + scol;
    const bf16* Bbase = B + (size_t)(n0 + srow + sr)*KDIM + scol;

    f32x4 acc[4][4] = {};
    char* bc = lds;             // compute buffer
    char* bn = lds + 32768;     // staging buffer

    auto STAGE = [&](char* buf, int kk) {
        #pragma unroll
        for (int c = 0; c < 4; c++) {
            gl_lds16(Abase + (size_t)(c*8)*KDIM + kk, buf + (srow + c*8)*128);
            gl_lds16(Bbase + (size_t)(c*8)*KDIM + kk, buf + 16384 + (srow + c*8)*128);
        }
    };

    STAGE(bc, 0);
    asm volatile("s_waitcnt vmcnt(0)" ::: "memory");
    __builtin_amdgcn_s_barrier();

    #pragma unroll
    for (int kt = 0; kt < NT; kt++) {
        if (kt + 1 < NT) STAGE(bn, (kt+1)*64);     // issue-early: lands under MFMA
        #pragma unroll
        for (int ks = 0; ks < 64; ks += 32) {
            bf16x8 a[4], b[4];
            #pragma unroll
            for (int mi=0;mi<4;mi++) {
                int ra = wm + mi*16 + lr;
                a[mi] = *(const bf16x8*)(bc + ra*128 + ((((ks>>3)+lg) ^ (ra&7))<<4));
            }
            #pragma unroll
            for (int ni=0;ni<4;ni++) {
                int rb = wn + ni*16 + lr;
                b[ni] = *(const bf16x8*)(bc + 16384 + rb*128 + ((((ks>>3)+lg) ^ (rb&7))<<4));
            }
            __builtin_amdgcn_s_setprio(1);
            #pragma unroll
            for (int mi=0;mi<4;mi++)
                #pragma unroll
                for (int ni=0;ni<4;ni++)
                    acc[mi][ni] = __builtin_amdgcn_mfma_f32_16x16x32_bf16(a[mi], b[ni], acc[mi][ni], 0,0,0);
            __builtin_amdgcn_s_setprio(0);
        }
        asm volatile("s_waitcnt vmcnt(0)" ::: "memory");   // this iter's stage: hidden
        __builtin_amdgcn_s_barrier();
        char* tb2 = bc; bc = bn; bn = tb2;
    }
    __builtin_amdgcn_sched_barrier(0);

    // repack C tile into LDS (bank-safe: stride 136) — staging buffers dead
    #pragma unroll
    for (int mi=0;mi<4;mi++)
        #pragma unroll
        for (int ni=0;ni<4;ni++)
            #pragma unroll
            for (int rr=0;rr<4;rr++)
                Cs[(wm+mi*16+lg*4+rr)*136 + wn+ni*16+lr] = f2b(acc[mi][ni][rr]);
    __syncthreads();

    const int rsub = t >> 4;            // 0..15
    const int c8   = (t & 15) * 8;      // constant per thread across store loop

    if (FUSE == 0 || n0 < 1024) {
        const int strd = (FUSE == 0) ? Nout : 1024;
        #pragma unroll
        for (int it = 0; it < 8; it++) {
            int row = it*16 + rsub;
            int gcol = n0 + c8;
            if (FUSE == 0 && gcol >= Nout) continue;
            *(uint4*)(C + (size_t)(m0+row)*strd + gcol) = *(const uint4*)&Cs[row*136 + c8];
        }
    } else if (n0 < 2304) {
        // depthwise causal conv + silu -> xbcc
        const int cbase = n0 - 1024 + c8;
        float4 wreg[8]; float bias[8];
        #pragma unroll
        for (int e=0;e<8;e++) wreg[e] = *(const float4*)(cw + (size_t)(cbase+e)*4);
        {
            float4 b0 = *(const float4*)(cb + cbase);
            float4 b1 = *(const float4*)(cb + cbase + 4);
            bias[0]=b0.x; bias[1]=b0.y; bias[2]=b0.z; bias[3]=b0.w;
            bias[4]=b1.x; bias[5]=b1.y; bias[6]=b1.z; bias[7]=b1.w;
        }
        #pragma unroll
        for (int it = 0; it < 8; it++) {
            int row = it*16 + rsub;
            int sl  = row & (SEQ-1);
            float m3 = (sl >= 3) ? 1.f : 0.f;
            float m2 = (sl >= 2) ? 1.f : 0.f;
            float m1 = (sl >= 1) ? 1.f : 0.f;
            const bf16* sm3 = &Cs[(row-3)*136 + c8];
            const bf16* sm2 = &Cs[(row-2)*136 + c8];
            const bf16* sm1 = &Cs[(row-1)*136 + c8];
            const bf16* sm0 = &Cs[(row  )*136 + c8];
            float a[8];
            #pragma unroll
            for (int e=0;e<8;e++) {
                a[e] = bias[e]
                     + m3 * b2f(sm3[e]) * wreg[e].x
                     + m2 * b2f(sm2[e]) * wreg[e].y
                     + m1 * b2f(sm1[e]) * wreg[e].z
                     +      b2f(sm0[e]) * wreg[e].w;
            }
            bf16 outv[8];
            #pragma unroll
            for (int e=0;e<8;e++) outv[e] = f2b(a[e] / (1.f + __expf(-a[e])));
            *(uint4*)(xbcc + (size_t)(m0+row)*CONV_DIM + cbase) = *(uint4*)&outv[0];
        }
    } else {
        // dt tile: softplus + cumsum scan over each sequence, write dt/cum f32
        for (int p = wid; p < 32; p += 4) {       // (seq-in-tile, head)
            int sq = p >> 4, head = p & 15;
            float raw = b2f(Cs[(sq*64 + lane)*136 + head]) + dt_bias[head];
            float dval = (raw > 20.f) ? raw : log1pf(__expf(raw));
            float Ah = -__expf(A_log[head]);
            float cc = dval * Ah;
            #pragma unroll
            for (int o=1;o<64;o<<=1) { float v = __shfl_up(cc, o); if (lane >= o) cc += v; }
            int tok = m0 + sq*64 + lane;
            dt [(size_t)head*ctok + tok] = dval;
            cum[(size_t)head*ctok + tok] = cc;
        }
    }
}

// ---------------- SSD core v2: MFMA for y = W @ xs ----------------
__global__ __launch_bounds__(256) void k_ssd(const bf16* __restrict__ xbcc,
        const float* __restrict__ dt, const float* __restrict__ cum,
        const float* __restrict__ Dskip, bf16* __restrict__ y, int ctok) {
    __shared__ float scores[64][66];                       // 16896 B
    __shared__ __align__(16) bf16 Wb [64][72];             // 9216 B
    __shared__ __align__(16) bf16 xsT[64][72];             // 9216 B
    __shared__ __align__(16) bf16 ys [64][72];             // 9216 B
    const int bid = blockIdx.x;
    const int b   = bid >> 1;
    const int hg  = (bid & 1) * 8;
    const int t = threadIdx.x;
    const size_t tokbase = (size_t)b*SEQ;
    const int lane = t & 63, lr = lane & 15, lg = lane >> 4;
    const int w = t >> 6;

    {   // scores via MFMA: wave w handles rows [w*16, w*16+16)
        int i0 = w*16;
        f32x4 sacc[4] = {};
        const bf16* Cbase = xbcc + tokbase*CONV_DIM + D_INNER + D_STATE;
        const bf16* Bbase = xbcc + tokbase*CONV_DIM + D_INNER;
        #pragma unroll
        for (int ks = 0; ks < D_STATE; ks += 32) {
            bf16x8 af = *(const bf16x8*)(Cbase + (size_t)(i0+lr)*CONV_DIM + ks + lg*8);
            #pragma unroll
            for (int jt = 0; jt < 4; jt++) {
                bf16x8 bfr = *(const bf16x8*)(Bbase + (size_t)(jt*16+lr)*CONV_DIM + ks + lg*8);
                sacc[jt] = __builtin_amdgcn_mfma_f32_16x16x32_bf16(af, bfr, sacc[jt], 0,0,0);
            }
        }
        #pragma unroll
        for (int jt=0;jt<4;jt++)
            #pragma unroll
            for (int rr=0;rr<4;rr++)
                scores[i0 + lg*4 + rr][jt*16 + lr] = sacc[jt][rr];
    }

    const int wi = t >> 2;
    const int wj0 = (t & 3) * 16;

    for (int hl = 0; hl < 8; hl++) {
        const int hh = hg + hl;
        const size_t cbase = (size_t)hh*ctok + tokbase;
        __syncthreads();

        // ---- phase 1: stage xsT (transpose) + build Wb ----
        #pragma unroll
        for (int cc = 0; cc < 2; cc++) {
            int ch = cc*256 + t;
            int rr = ch >> 3, c8 = (ch & 7)*8;
            uint4 v = *(const uint4*)(xbcc + (tokbase + rr)*CONV_DIM + hh*HEADDIM + c8);
            const bf16* pv = (const bf16*)&v;
            #pragma unroll
            for (int e=0;e<8;e++) xsT[c8+e][rr] = pv[e];
        }
        {
            float cum_i = cum[cbase + wi];
            float cjf[16], djf[16];
            #pragma unroll
            for (int qq=0; qq<4; qq++) {
                float4 a4 = *(const float4*)(cum + cbase + wj0 + qq*4);
                float4 d4 = *(const float4*)(dt  + cbase + wj0 + qq*4);
                cjf[qq*4+0]=a4.x; cjf[qq*4+1]=a4.y; cjf[qq*4+2]=a4.z; cjf[qq*4+3]=a4.w;
                djf[qq*4+0]=d4.x; djf[qq*4+1]=d4.y; djf[qq*4+2]=d4.z; djf[qq*4+3]=d4.w;
            }
            bf16 tb[16];
            #pragma unroll
            for (int e=0;e<16;e++) {
                int j = wj0 + e;
                float wv = (j <= wi) ? scores[wi][j] * __expf(cum_i - cjf[e]) * djf[e] : 0.f;
                tb[e] = f2b(wv);
            }
            *(uint4*)&Wb[wi][wj0]   = *(uint4*)&tb[0];
            *(uint4*)&Wb[wi][wj0+8] = *(uint4*)&tb[8];
        }
        __syncthreads();

        // ---- phase 2: MFMA y = Wb @ xsT^T, + D_skip*xs, write ys ----
        {
            float dsk = Dskip[hh];
            f32x4 yacc[4] = {};
            #pragma unroll
            for (int ks = 0; ks < 64; ks += 32) {
                bf16x8 a = *(const bf16x8*)&Wb[w*16 + lr][ks + lg*8];
                #pragma unroll
                for (int n=0; n<4; n++) {
                    bf16x8 bb = *(const bf16x8*)&xsT[n*16 + lr][ks + lg*8];
                    yacc[n] = __builtin_amdgcn_mfma_f32_16x16x32_bf16(a, bb, yacc[n], 0,0,0);
                }
            }
            #pragma unroll
            for (int n=0; n<4; n++)
                #pragma unroll
                for (int rr=0; rr<4; rr++) {
                    int row = w*16 + lg*4 + rr;
                    int col = n*16 + lr;
                    ys[row][col] = f2b(yacc[n][rr] + dsk * b2f(xsT[col][row]));
                }
        }
        __syncthreads();

        // ---- phase 3: coalesced store ys -> ybuf ----
        #pragma unroll
        for (int cc = 0; cc < 2; cc++) {
            int ch = cc*256 + t;
            int rr = ch >> 3, c8 = (ch & 7)*8;
            *(uint4*)(y + (tokbase + rr)*D_INNER + hh*HEADDIM + c8) = *(const uint4*)&ys[rr][c8];
        }
    }
}

// ---------------- y = y*silu(z); RMS-norm * norm_w (in place, bf16) ----------------
__global__ __launch_bounds__(256) void k_gaterms(bf16* __restrict__ y,
        const bf16* __restrict__ zbuf, const float* __restrict__ nw) {
    int tok = blockIdx.x, t = threadIdx.x;
    __shared__ float red[4];
    int d = t*4;
    uint2 yv = *(const uint2*)(y    + (size_t)tok*D_INNER + d);
    uint2 zv = *(const uint2*)(zbuf + (size_t)tok*D_INNER + d);
    const unsigned* yu = (const unsigned*)&yv;
    const unsigned* zu = (const unsigned*)&zv;
    float g[4]; float ss = 0.f;
    #pragma unroll
    for (int e=0;e<2;e++) {
        float y0 = bflo(yu[e]), y1 = bfhi(yu[e]);
        float z0 = bflo(zu[e]), z1 = bfhi(zu[e]);
        float g0 = y0 * z0 / (1.f + __expf(-z0));
        float g1 = y1 * z1 / (1.f + __expf(-z1));
        g[2*e] = g0; g[2*e+1] = g1;
        ss += g0*g0 + g1*g1;
    }
    for (int o=32;o>0;o>>=1) ss += __shfl_down(ss, o);
    if ((t & 63) == 0) red[t>>6] = ss;
    __syncthreads();
    float tot = red[0]+red[1]+red[2]+red[3];
    float scale = rsqrtf(tot/(float)D_INNER + EPS);
    bf16 outv[4];
    #pragma unroll
    for (int e=0;e<4;e++) outv[e] = f2b(g[e] * scale * nw[d+e]);
    *(uint2*)(y + (size_t)tok*D_INNER + d) = *(uint2*)&outv[0];
}

// ---------------- h += layernorm(tmp)*g + b; refresh hb ----------------
__global__ __launch_bounds__(256) void k_resln(float* __restrict__ h,
        bf16* __restrict__ hb, const bf16* __restrict__ tmp,
        const float* __restrict__ g, const float* __restrict__ bb) {
    int tok = blockIdx.x, t = threadIdx.x;
    __shared__ float redS[4], redQ[4];
    int d = t*2;
    unsigned u = *(const unsigned*)(tmp + (size_t)tok*D_MODEL + d);
    float v0 = bflo(u), v1 = bfhi(u);
    float s = v0+v1, q = v0*v0+v1*v1;
    for (int o=32;o>0;o>>=1){ s += __shfl_down(s,o); q += __shfl_down(q,o); }
    if ((t&63)==0){ redS[t>>6]=s; redQ[t>>6]=q; }
    __syncthreads();
    float S = redS[0]+redS[1]+redS[2]+redS[3];
    float Q = redQ[0]+redQ[1]+redQ[2]+redQ[3];
    float mu  = S/(float)D_MODEL;
    float var = Q/(float)D_MODEL - mu*mu;
    float inv = rsqrtf(var + EPS);
    size_t base = (size_t)tok*D_MODEL + d;
    float h0 = h[base]   + (v0-mu)*inv*g[d]   + bb[d];
    float h1 = h[base+1] + (v1-mu)*inv*g[d+1] + bb[d+1];
    h[base] = h0; h[base+1] = h1;
    bf16 o2[2] = { f2b(h0), f2b(h1) };
    *(unsigned*)(hb + base) = *(unsigned*)&o2[0];
}

// ---------------- masked mean-pool over s ----------------
__global__ __launch_bounds__(256) void k_pool(const float* __restrict__ h,
        float* __restrict__ pooled) {
    int b = blockIdx.x, t = threadIdx.x;
    __shared__ float ps[64][4];
    __shared__ float pm[64];
    __shared__ float cntS;
    {
        int s = t >> 2, q = t & 3;
        const float4* row = (const float4*)(h + ((size_t)b*SEQ + s)*D_MODEL + q*128);
        float acc = 0;
        #pragma unroll 8
        for (int e=0;e<32;e++) { float4 f = row[e]; acc += f.x+f.y+f.z+f.w; }
        ps[s][q] = acc;
    }
    __syncthreads();
    if (t < 64) pm[t] = (ps[t][0]+ps[t][1]+ps[t][2]+ps[t][3]) != 0.f ? 1.f : 0.f;
    __syncthreads();
    if (t == 0) { float c=0; for (int s2=0;s2<64;s2++) c+=pm[s2]; cntS = fmaxf(c,1.f); }
    __syncthreads();
    float cnt = cntS;
    #pragma unroll
    for (int rep=0;rep<2;rep++) {
        int d = t + rep*256;
        float acc = 0;
        for (int s2=0;s2<64;s2++) acc += h[((size_t)b*SEQ+s2)*D_MODEL + d] * pm[s2];
        pooled[(size_t)b*D_MODEL + d] = acc / cnt;
    }
}

// ---------------- fc1(relu) + fc2 ----------------
__global__ __launch_bounds__(128) void k_fc(const float* __restrict__ pooled,
        const float* __restrict__ w1, const float* __restrict__ b1,
        const float* __restrict__ w2, const float* __restrict__ b2,
        float* __restrict__ out) {
    int b = blockIdx.x, j = threadIdx.x;
    __shared__ float hid[FC_HID];
    const float* p  = pooled + (size_t)b*D_MODEL;
    const float* wr = w1 + (size_t)j*D_MODEL;
    float acc = b1[j];
    for (int d=0; d<D_MODEL; d+=4)
        acc += p[d]*wr[d] + p[d+1]*wr[d+1] + p[d+2]*wr[d+2] + p[d+3]*wr[d+3];
    hid[j] = fmaxf(acc, 0.f);
    __syncthreads();
    if (j < 2) {
        float o = b2[j];
        for (int k=0;k<FC_HID;k++) o += hid[k]*w2[j*FC_HID+k];
        out[b*2 + j] = o;
    }
}

extern "C" void kernel_launch(void* const* d_in, const int* in_sizes, int n_in,
                              void* d_out, int out_size, void* d_ws, size_t ws_size,
                              hipStream_t stream) {
    (void)in_sizes; (void)n_in; (void)out_size;
    const int*   x        = (const int*)  d_in[0];
    const float* emb      = (const float*)d_in[1];
    const float* pos      = (const float*)d_in[2];
    const float* in_proj  = (const float*)d_in[3];
    const float* conv_w   = (const float*)d_in[4];
    const float* conv_b   = (const float*)d_in[5];
    const float* dt_bias  = (const float*)d_in[6];
    const float* A_log    = (const float*)d_in[7];
    const float* D_skip   = (const float*)d_in[8];
    const float* norm_w   = (const float*)d_in[9];
    const float* out_proj = (const float*)d_in[10];
    const float* ln_g     = (const float*)d_in[11];
    const float* ln_b     = (const float*)d_in[12];
    const float* fc1_w    = (const float*)d_in[13];
    const float* fc1_b    = (const float*)d_in[14];
    const float* fc2_w    = (const float*)d_in[15];
    const float* fc2_b    = (const float*)d_in[16];
    float* out = (float*)d_out;

    // ---- persistent region ----
    const size_t H_B   = (size_t)NTOK * D_MODEL * 4;     // 64 MB f32 h
    const size_t HB_B  = (size_t)NTOK * D_MODEL * 2;     // 32 MB bf16 shadow
    const size_t WPI_B = (size_t)NPAD * D_MODEL * 2;     // per layer 2.49 MB
    const size_t WPO_B = (size_t)D_MODEL * D_INNER * 2;  // per layer 1 MB
    const size_t PBASE = H_B + HB_B + NLAYERS*(WPI_B + WPO_B);

    // transients per token: z 2048 + xbcc 2560 + ybuf 2048 + dt/cum 128
    const size_t PER_TOK = 2048 + 2560 + 2048 + 128;     // 6784 B
    int CB = BATCH;
    while (CB > 8 && PBASE + (size_t)CB*SEQ*PER_TOK > ws_size) CB >>= 1;
    const int CT = CB * SEQ;
    const int NC = BATCH / CB;

    char* ws = (char*)d_ws;
    float* h    = (float*)(ws);
    bf16*  hb   = (bf16*) (ws + H_B);
    bf16*  wpi  = (bf16*) (ws + H_B + HB_B);                   // [NLAYERS][NPAD][512]
    bf16*  wpo  = (bf16*) (ws + H_B + HB_B + NLAYERS*WPI_B);   // [NLAYERS][512][1024]
    char*  tr   = ws + PBASE;
    bf16*  zbuf = (bf16*) (tr);                                // CT*1024
    bf16*  xbcc = (bf16*) (tr + (size_t)CT*2048);              // CT*1280
    bf16*  ybuf = (bf16*) (tr + (size_t)CT*(2048+2560));       // CT*1024
    float* dt   = (float*)(tr + (size_t)CT*(2048+2560+2048));  // [16][CT]
    float* cum  = dt + (size_t)CT*NHEADS;
    bf16*  tmp  = xbcc;                 // alias: xbcc dead after k_ssd
    float* pooled = (float*)tr;

    // weight conversion (both layers, once per launch)
    for (int l = 0; l < NLAYERS; l++) {
        int t8i = NPAD*D_MODEL/8;
        k_cvtw<<<(t8i+255)/256, 256, 0, stream>>>(in_proj + (size_t)l*D_IN_PROJ*D_MODEL,
                wpi + (size_t)l*NPAD*D_MODEL, D_IN_PROJ, D_MODEL, t8i);
        int t8o = D_MODEL*D_INNER/8;
        k_cvtw<<<(t8o+255)/256, 256, 0, stream>>>(out_proj + (size_t)l*D_MODEL*D_INNER,
                wpo + (size_t)l*D_MODEL*D_INNER, D_MODEL, D_INNER, t8o);
    }

    k_embed<<<(NTOK*D_MODEL)/256, 256, 0, stream>>>(x, emb, pos, h, hb);

    const int NBX_I = NPAD/128;     // 19
    const int NBX_O = D_MODEL/128;  // 4

    for (int l = 0; l < NLAYERS; l++) {
        const bf16* wi = wpi + (size_t)l*NPAD*D_MODEL;
        const bf16* wo = wpo + (size_t)l*D_MODEL*D_INNER;
        for (int c = 0; c < NC; c++) {
            const int tok0 = c * CT;
            float* hc  = h  + (size_t)tok0 * D_MODEL;
            bf16*  hbc = hb + (size_t)tok0 * D_MODEL;
            k_gemm128<1,512><<<(CT/128)*NBX_I, 256, 0, stream>>>(hbc, wi, zbuf,
                    xbcc, dt, cum,
                    conv_w + (size_t)l*CONV_DIM*D_CONV, conv_b + (size_t)l*CONV_DIM,
                    dt_bias + l*NHEADS, A_log + l*NHEADS,
                    NPAD, NBX_I, CT);
            k_ssd<<<CB*2, 256, 0, stream>>>(xbcc, dt, cum, D_skip + l*NHEADS, ybuf, CT);
            k_gaterms<<<CT, 256, 0, stream>>>(ybuf, zbuf, norm_w + (size_t)l*D_INNER);
            k_gemm128<0,1024><<<(CT/128)*NBX_O, 256, 0, stream>>>(ybuf, wo, tmp,
                    nullptr, nullptr, nullptr, nullptr, nullptr, nullptr, nullptr,
                    D_MODEL, NBX_O, CT);
            k_resln<<<CT, 256, 0, stream>>>(hc, hbc, tmp, ln_g + l*D_MODEL, ln_b + l*D_MODEL);
        }
    }

    k_pool<<<BATCH, 256, 0, stream>>>(h, pooled);
    k_fc<<<BATCH, FC_HID, 0, stream>>>(pooled, fc1_w, fc1_b, fc2_w, fc2_b, out);
}